// Round 4
// baseline (420.946 us; speedup 1.0000x reference)
//
#include <hip/hip_runtime.h>
#include <math.h>

constexpr int B_  = 8;
constexpr int N_  = 1025;
constexpr int D_  = 1024;
constexpr int H_  = 16;
constexpr int M_  = B_ * N_;   // 8200 rows
constexpr int K3_ = 3 * D_;    // 3072
constexpr int NP_ = 1088;      // padded key count (17 * 64)

constexpr float LOG2E = 1.4426950408889634f;

typedef short  v8s __attribute__((ext_vector_type(8)));
typedef short  v4s __attribute__((ext_vector_type(4)));
typedef float  v4f __attribute__((ext_vector_type(4)));

__device__ __forceinline__ float wave_sum64(float v) {
#pragma unroll
  for (int o = 32; o; o >>= 1) v += __shfl_xor(v, o, 64);
  return v;
}

__device__ __forceinline__ unsigned short f2bf(float f) {
  unsigned u = __float_as_uint(f);
  u += 0x7FFFu + ((u >> 16) & 1u);
  return (unsigned short)(u >> 16);
}

__device__ __forceinline__ float bf2f(unsigned short s) {
  return __uint_as_float(((unsigned)s) << 16);
}

// raw v_exp_f32: computes 2^x (no base-conversion mul)
__device__ __forceinline__ float fexp2(float x) {
  float r;
  asm("v_exp_f32 %0, %1" : "=v"(r) : "v"(x));
  return r;
}

// async 16B global -> LDS (wave-uniform lds base + lane*16; global addr per-lane)
__device__ __forceinline__ void gload16(const unsigned short* g, unsigned short* l) {
  __builtin_amdgcn_global_load_lds(
      (const __attribute__((address_space(1))) unsigned int*)g,
      (__attribute__((address_space(3))) unsigned int*)l, 16, 0, 0);
}

// bijective XCD-chunked block-id swizzle (m204): consecutive logical ids land
// on the same XCD -> A/B-panel L2 reuse. Valid for any nwg.
__device__ __forceinline__ int xcd_swz(int id, int nwg) {
  const int q = nwg >> 3, r = nwg & 7;
  const int x = id & 7, o = id >> 3;
  return (x < r ? x * (q + 1) : r * (q + 1) + (x - r) * q) + o;
}

// ---------------- fp32 -> bf16 convert (all 3 weight mats, 1 launch) --------
__global__ __launch_bounds__(256) void k_f2bf_all(const float* __restrict__ w0,
                                                  const float* __restrict__ w1,
                                                  const float* __restrict__ w2,
                                                  unsigned short* __restrict__ d0,
                                                  unsigned short* __restrict__ d1,
                                                  unsigned short* __restrict__ d2)
{
  const int n0 = K3_ * D_, n1 = D_ * D_;
  int i = (blockIdx.x * 256 + threadIdx.x) * 4;
  const float* s; unsigned short* d;
  if (i < n0)            { s = w0;            d = d0;            }
  else if (i < n0 + n1)  { s = w1; i -= n0;   d = d1;            }
  else                   { s = w2; i -= n0 + n1; d = d2;         }
  const float4 v = *(const float4*)(s + i);
  ushort4 o;
  o.x = f2bf(v.x); o.y = f2bf(v.y); o.z = f2bf(v.z); o.w = f2bf(v.w);
  *(ushort4*)(d + i) = o;
}

// ---------------- zero-centered RMSNorm -> bf16 ----------------
__global__ __launch_bounds__(256) void k_rmsnorm(const float* __restrict__ X,
                                                 const float* __restrict__ gw,
                                                 unsigned short* __restrict__ Hb)
{
  const int m = blockIdx.x;
  const int t = threadIdx.x;
  const int wid = t >> 6, lane = t & 63;
  __shared__ float red[4];

  const float4 v = ((const float4*)(X + (size_t)m * D_))[t];
  float s = wave_sum64(v.x + v.y + v.z + v.w);
  if (lane == 0) red[wid] = s;
  __syncthreads();
  const float mean = (red[0] + red[1] + red[2] + red[3]) * (1.0f / (float)D_);

  const float4 x0 = make_float4(v.x - mean, v.y - mean, v.z - mean, v.w - mean);
  float ss = wave_sum64(x0.x * x0.x + x0.y * x0.y + x0.z * x0.z + x0.w * x0.w);
  __syncthreads();
  if (lane == 0) red[wid] = ss;
  __syncthreads();
  const float inv = rsqrtf((red[0] + red[1] + red[2] + red[3]) * (1.0f / (float)D_) + 1e-8f);

  const float4 gv = ((const float4*)gw)[t];
  ushort4 o;
  o.x = f2bf(x0.x * inv * gv.x);  o.y = f2bf(x0.y * inv * gv.y);
  o.z = f2bf(x0.z * inv * gv.z);  o.w = f2bf(x0.w * inv * gv.w);
  ((ushort4*)(Hb + (size_t)m * D_))[t] = o;
}

// ---------------- 256x256 deep-pipelined bf16 MFMA GEMM ----------------
// 8 waves (2M x 4N, 128x64 out/wave), BK=64, 128KB double-buffered LDS,
// XOR-swizzled chunks, staging 2 K-tiles ahead with counted vmcnt(8),
// quadrant-phase MFMA with s_setprio, XCD-chunked block swizzle.
template<int EPI>
__global__ __launch_bounds__(512, 2) void k_gemm256(
    const unsigned short* __restrict__ A,
    const unsigned short* __restrict__ Wt,
    const float* __restrict__ bias,
    float* __restrict__ C,
    const float* __restrict__ ZO,
    const float* __restrict__ X,
    int Mrows, int Ncols, int K)
{
  __shared__ __align__(16) unsigned short As[2][256 * 64];   // 64 KB
  __shared__ __align__(16) unsigned short Bs[2][256 * 64];   // 64 KB

  const int t    = threadIdx.x;
  const int w    = t >> 6;            // 0..7
  const int lane = t & 63;
  const int l15  = lane & 15;
  const int quad = lane >> 4;
  const int wr   = w >> 2;            // 0..1 (M)
  const int wc   = w & 3;             // 0..3 (N)

  const int nwg = gridDim.x * gridDim.y;
  const int lid = xcd_swz(blockIdx.x + gridDim.x * blockIdx.y, nwg);
  const int m0  = (lid / gridDim.x) * 256;
  const int n0  = (lid % gridDim.x) * 256;

  const int rl = lane >> 3;           // staging row within 8-row group
  const int cg = (lane & 7) ^ rl;     // pre-swizzled source chunk (involution)

  auto stageA = [&](int bb, int ktile, int h) {
#pragma unroll
    for (int cc = 0; cc < 2; ++cc) {
      const int rt = h * 128 + cc * 64 + w * 8;
      const int gr = min(m0 + rt + rl, Mrows - 1);
      gload16(A + (size_t)gr * K + ktile * 64 + cg * 8, &As[bb][rt * 64]);
    }
  };
  auto stageB = [&](int bb, int ktile, int h) {
#pragma unroll
    for (int cc = 0; cc < 2; ++cc) {
      const int rt = h * 128 + cc * 64 + w * 8;
      gload16(Wt + (size_t)(n0 + rt + rl) * K + ktile * 64 + cg * 8, &Bs[bb][rt * 64]);
    }
  };

  v4f acc[8][4];
#pragma unroll
  for (int i = 0; i < 8; ++i)
#pragma unroll
    for (int j = 0; j < 4; ++j) acc[i][j] = (v4f){0.f, 0.f, 0.f, 0.f};

  const int NT = K >> 6;   // 16 for K=1024

  // prologue: stage tiles 0 and 1 (8 loads/wave each)
  stageA(0, 0, 0); stageA(0, 0, 1); stageB(0, 0, 0); stageB(0, 0, 1);
  stageA(1, 1, 0); stageA(1, 1, 1); stageB(1, 1, 0); stageB(1, 1, 1);

  const int arow = wr * 128;
  const int brow = wc * 64;

  for (int kt = 0; kt < NT; ++kt) {
    const int bb = kt & 1;
    if (kt < NT - 1) asm volatile("s_waitcnt vmcnt(8)" ::: "memory");
    else             asm volatile("s_waitcnt vmcnt(0)" ::: "memory");
    __builtin_amdgcn_s_barrier();

    const bool pf = (kt + 2 < NT);

    // ---- P0: ds_read A rows 0..63 + all B; MFMA quadrant (0,lo) ----
    v8s a[4][2], bq[4][2];
#pragma unroll
    for (int mf = 0; mf < 4; ++mf) {
      const int r = arow + mf * 16 + l15;
#pragma unroll
      for (int kc = 0; kc < 2; ++kc)
        a[mf][kc] = *(const v8s*)&As[bb][r * 64 + (((kc * 4 + quad) ^ (l15 & 7)) * 8)];
    }
#pragma unroll
    for (int nf = 0; nf < 4; ++nf) {
      const int r = brow + nf * 16 + l15;
#pragma unroll
      for (int kc = 0; kc < 2; ++kc)
        bq[nf][kc] = *(const v8s*)&Bs[bb][r * 64 + (((kc * 4 + quad) ^ (l15 & 7)) * 8)];
    }
    asm volatile("s_waitcnt lgkmcnt(0)" ::: "memory");
    __builtin_amdgcn_s_barrier();
    __builtin_amdgcn_s_setprio(1);
#pragma unroll
    for (int mf = 0; mf < 4; ++mf)
#pragma unroll
      for (int nf = 0; nf < 2; ++nf)
#pragma unroll
        for (int kc = 0; kc < 2; ++kc)
          acc[mf][nf] = __builtin_amdgcn_mfma_f32_16x16x32_bf16(a[mf][kc], bq[nf][kc], acc[mf][nf], 0, 0, 0);
    __builtin_amdgcn_s_setprio(0);
    __builtin_amdgcn_s_barrier();

    // ---- P1: prefetch B-half0(kt+2); MFMA quadrant (0,hi) ----
    if (pf) stageB(bb, kt + 2, 0);
    __builtin_amdgcn_s_setprio(1);
#pragma unroll
    for (int mf = 0; mf < 4; ++mf)
#pragma unroll
      for (int nf = 2; nf < 4; ++nf)
#pragma unroll
        for (int kc = 0; kc < 2; ++kc)
          acc[mf][nf] = __builtin_amdgcn_mfma_f32_16x16x32_bf16(a[mf][kc], bq[nf][kc], acc[mf][nf], 0, 0, 0);
    __builtin_amdgcn_s_setprio(0);
    __builtin_amdgcn_s_barrier();

    // ---- P2: ds_read A rows 64..127; prefetch B-half1; MFMA (1,lo) ----
#pragma unroll
    for (int mf = 0; mf < 4; ++mf) {
      const int r = arow + 64 + mf * 16 + l15;
#pragma unroll
      for (int kc = 0; kc < 2; ++kc)
        a[mf][kc] = *(const v8s*)&As[bb][r * 64 + (((kc * 4 + quad) ^ (l15 & 7)) * 8)];
    }
    if (pf) stageB(bb, kt + 2, 1);
    asm volatile("s_waitcnt lgkmcnt(0)" ::: "memory");
    __builtin_amdgcn_s_barrier();
    __builtin_amdgcn_s_setprio(1);
#pragma unroll
    for (int mf = 0; mf < 4; ++mf)
#pragma unroll
      for (int nf = 0; nf < 2; ++nf)
#pragma unroll
        for (int kc = 0; kc < 2; ++kc)
          acc[4 + mf][nf] = __builtin_amdgcn_mfma_f32_16x16x32_bf16(a[mf][kc], bq[nf][kc], acc[4 + mf][nf], 0, 0, 0);
    __builtin_amdgcn_s_setprio(0);
    __builtin_amdgcn_s_barrier();

    // ---- P3: prefetch A halves(kt+2); MFMA quadrant (1,hi) ----
    if (pf) { stageA(bb, kt + 2, 0); stageA(bb, kt + 2, 1); }
    __builtin_amdgcn_s_setprio(1);
#pragma unroll
    for (int mf = 0; mf < 4; ++mf)
#pragma unroll
      for (int nf = 2; nf < 4; ++nf)
#pragma unroll
        for (int kc = 0; kc < 2; ++kc)
          acc[4 + mf][nf] = __builtin_amdgcn_mfma_f32_16x16x32_bf16(a[mf][kc], bq[nf][kc], acc[4 + mf][nf], 0, 0, 0);
    __builtin_amdgcn_s_setprio(0);
  }

  float cb[4];
#pragma unroll
  for (int nf = 0; nf < 4; ++nf) cb[nf] = bias[n0 + brow + nf * 16 + l15];

#pragma unroll
  for (int mf = 0; mf < 8; ++mf) {
    const int rbase = m0 + arow + mf * 16 + quad * 4;
#pragma unroll
    for (int c = 0; c < 4; ++c) {
      const int row = rbase + c;
      if (row < Mrows) {
#pragma unroll
        for (int nf = 0; nf < 4; ++nf) {
          const size_t idx = (size_t)row * Ncols + n0 + brow + nf * 16 + l15;
          if (EPI == 0) {
            C[idx] = acc[mf][nf][c] + cb[nf];
          } else {
            const float zg = acc[mf][nf][c] + cb[nf];
            const float sg = 1.0f / (1.0f + __expf(-zg));
            C[idx] = X[idx] + sg * ZO[idx];
          }
        }
      }
    }
  }
}

// ---------------- fused Q/K rope + Q/K/V bf16 repack ----------------
// Q is pre-scaled by 1/sqrt(Dh) * log2(e) so attention can use raw v_exp_f32.
__global__ __launch_bounds__(256) void k_repack_qkv(const float* __restrict__ qkv,
                                                    const float* __restrict__ fc,
                                                    unsigned short* __restrict__ qt,
                                                    unsigned short* __restrict__ kt,
                                                    unsigned short* __restrict__ vt)
{
  const int bh = blockIdx.x;
  const int b  = bh >> 4;
  const int h  = bh & 15;
  const int j0 = blockIdx.y * 64;
  const int t  = threadIdx.x;
  __shared__ float T[64][65];

  // ---- Q and K: rope -> [bh][j][d] ----
  {
    const int row  = t >> 2;
    const int dseg = (t & 3) * 16;
    const int n    = j0 + row;
    unsigned short qb[16], kb[16];
    if (n < N_) {
      const float2* qp = (const float2*)(qkv + (size_t)(b * N_ + n) * K3_ + h * 64 + dseg);
      const float2* kp = (const float2*)(qkv + (size_t)(b * N_ + n) * K3_ + 1024 + h * 64 + dseg);
      const float2* fp = (const float2*)fc + (size_t)n * 32 + dseg / 2;
      const float qs = 0.125f * LOG2E;
#pragma unroll
      for (int j = 0; j < 8; ++j) {
        const float2 f  = fp[j];
        const float2 qv = qp[j];
        qb[2 * j]     = f2bf((qv.x * f.x - qv.y * f.y) * qs);
        qb[2 * j + 1] = f2bf((qv.x * f.y + qv.y * f.x) * qs);
        const float2 kv = kp[j];
        kb[2 * j]     = f2bf(kv.x * f.x - kv.y * f.y);
        kb[2 * j + 1] = f2bf(kv.x * f.y + kv.y * f.x);
      }
    } else {
#pragma unroll
      for (int j = 0; j < 16; ++j) { qb[j] = 0; kb[j] = 0; }
    }
    unsigned short* qd = qt + ((size_t)bh * NP_ + j0 + row) * 64 + dseg;
    *(uint4*)qd       = *(uint4*)&qb[0];
    *(uint4*)(qd + 8) = *(uint4*)&qb[8];
    unsigned short* kd = kt + ((size_t)bh * NP_ + j0 + row) * 64 + dseg;
    *(uint4*)kd       = *(uint4*)&kb[0];
    *(uint4*)(kd + 8) = *(uint4*)&kb[8];
  }

  // ---- V: transpose -> vt[bh][d][j] ----
#pragma unroll
  for (int l = 0; l < 4; ++l) {
    const int j  = (t >> 4) + 16 * l;
    const int jg = j0 + j;
    const int d4 = (t & 15) * 4;
    float4 v = make_float4(0.f, 0.f, 0.f, 0.f);
    if (jg < N_) v = *(const float4*)(qkv + (size_t)(b * N_ + jg) * K3_ + 2048 + h * 64 + d4);
    *(float4*)&T[j][d4] = v;
  }
  __syncthreads();
#pragma unroll
  for (int l = 0; l < 4; ++l) {
    const int d  = (t >> 4) + 16 * l;
    const int j4 = (t & 15) * 4;
    ushort4 o;
    o.x = f2bf(T[j4 + 0][d]); o.y = f2bf(T[j4 + 1][d]);
    o.z = f2bf(T[j4 + 2][d]); o.w = f2bf(T[j4 + 3][d]);
    *(ushort4*)(vt + ((size_t)bh * 64 + d) * NP_ + j0 + j4) = o;
  }
}

// ---------------- MFMA flash attention (rows 0..1023) ----------------
// S computed TRANSPOSED (A=K, B=Q): S^T per-lane layout j=quad*4+reg, i=l15
// == A-operand layout of mfma_f32_16x16x16_bf16 -> PV directly from registers.
// Softmax in log2 domain (Q pre-scaled by log2e): bare v_exp_f32.
// Denominator via MFMA against all-ones B fragment (row-sums land in the
// exact epilogue lane slots). No setprio (measured -3us, R2 vs R3 A/B).
__global__ __launch_bounds__(256, 3) void k_attn_mfma(const unsigned short* __restrict__ qt,
                                                      const unsigned short* __restrict__ kt,
                                                      const unsigned short* __restrict__ vt,
                                                      const float* __restrict__ Bbias,
                                                      unsigned short* __restrict__ Y)
{
  const int bh = blockIdx.x;
  const int b  = bh >> 4;
  const int i0 = blockIdx.y * 128;     // 0..896: all rows < 1024 valid
  const int t  = threadIdx.x;
  const int wr = t >> 6;
  const int lane = t & 63;
  const int l15  = lane & 15;
  const int quad = lane >> 4;

  __shared__ __align__(16) unsigned short Ks[2][64 * 64];   // XOR-swizzled [j][d]
  __shared__ __align__(16) unsigned short Vs[2][64 * 64];   // XOR-swizzled [d][j]

  // ---- Q fragments (B-operand; pre-scaled by 1/8 * log2e) ----
  v8s qf[2][2];
#pragma unroll
  for (int rt = 0; rt < 2; ++rt)
#pragma unroll
    for (int ks = 0; ks < 2; ++ks) {
      const int row = i0 + wr * 32 + rt * 16 + l15;
      qf[rt][ks] = *(const v8s*)(qt + ((size_t)bh * NP_ + row) * 64 + ks * 32 + quad * 8);
    }

  // ---- per-lane tridiagonal bias, pre-scaled to log2 domain ----
  int   rowi[2];
  float bm[2], bp[2];
#pragma unroll
  for (int rt = 0; rt < 2; ++rt) {
    const int r = i0 + wr * 32 + rt * 16 + l15;
    rowi[rt] = r;
    bm[rt] = (r > 0) ? Bbias[(size_t)r * N_ + r - 1] * LOG2E : 0.f;
    bp[rt] = Bbias[(size_t)r * N_ + r + 1] * LOG2E;   // r <= 1023 < N_-1 always
  }

  v4f o[2][4];
  v4f ol[2];   // softmax denominator accumulators (row-sums via ones-MFMA)
#pragma unroll
  for (int rt = 0; rt < 2; ++rt) {
    ol[rt] = (v4f){0.f, 0.f, 0.f, 0.f};
#pragma unroll
    for (int nt = 0; nt < 4; ++nt) o[rt][nt] = (v4f){0.f, 0.f, 0.f, 0.f};
  }
  const v4s ones = { (short)0x3F80, (short)0x3F80, (short)0x3F80, (short)0x3F80 };

  const unsigned short* ktb = kt + (size_t)bh * NP_ * 64;
  const unsigned short* vtb = vt + (size_t)bh * 64 * NP_;
  const int rw0  = i0 + wr * 32;
  const int rowl = lane >> 3;          // 0..7
  const int lc   = (lane & 7) ^ rowl;  // XOR swizzle (16B chunk granularity)

  auto stage = [&](int ic, int pp) {
    const int js = ic * 64;
    gload16(ktb + (size_t)(js + wr * 16 + rowl) * 64 + lc * 8,      &Ks[pp][(wr * 16) * 64]);
    gload16(ktb + (size_t)(js + wr * 16 + 8 + rowl) * 64 + lc * 8,  &Ks[pp][(wr * 16 + 8) * 64]);
    gload16(vtb + (size_t)(wr * 16 + rowl) * NP_ + js + lc * 8,     &Vs[pp][(wr * 16) * 64]);
    gload16(vtb + (size_t)(wr * 16 + 8 + rowl) * NP_ + js + lc * 8, &Vs[pp][(wr * 16 + 8) * 64]);
  };

  stage(0, 0);   // prologue prefetch

  for (int ic = 0; ic < 17; ++ic) {
    const int j0 = ic * 64;
    const int p  = ic & 1;
    __builtin_amdgcn_s_waitcnt(0x0f70);   // vmcnt(0): chunk ic landed
    __syncthreads();
    if (ic < 16) stage(ic + 1, p ^ 1);    // prefetch next; overlaps compute below

    // ---- QK^T transposed: S^T[j][i] (already in log2 domain) ----
    v4f s[2][4];
#pragma unroll
    for (int jt = 0; jt < 4; ++jt) {
      const int rr  = jt * 16 + l15;
      const v8s kf0 = *(const v8s*)&Ks[p][rr * 64 + ((0 + quad) ^ (rr & 7)) * 8];
      const v8s kf1 = *(const v8s*)&Ks[p][rr * 64 + ((4 + quad) ^ (rr & 7)) * 8];
#pragma unroll
      for (int rt = 0; rt < 2; ++rt) {
        v4f acc = (v4f){0.f, 0.f, 0.f, 0.f};
        acc = __builtin_amdgcn_mfma_f32_16x16x32_bf16(kf0, qf[rt][0], acc, 0, 0, 0);
        acc = __builtin_amdgcn_mfma_f32_16x16x32_bf16(kf1, qf[rt][1], acc, 0, 0, 0);
        s[rt][jt] = acc;
      }
    }

    // ---- sparse tridiagonal bias (wave-uniform rare branch) ----
    if (j0 <= rw0 + 32 && j0 + 64 >= rw0) {
#pragma unroll
      for (int rt = 0; rt < 2; ++rt) {
        const int r = rowi[rt];
#pragma unroll
        for (int jt = 0; jt < 4; ++jt)
#pragma unroll
          for (int c = 0; c < 4; ++c) {
            const int j = j0 + jt * 16 + quad * 4 + c;
            float v = s[rt][jt][c];
            v += (j == r - 1) ? bm[rt] : 0.f;
            v += (j == r + 1) ? bp[rt] : 0.f;
            s[rt][jt][c] = v;
          }
      }
    }
    // ---- key mask (final chunk: padded j rows) ----
    if (ic == 16) {
#pragma unroll
      for (int jt = 0; jt < 4; ++jt)
#pragma unroll
        for (int c = 0; c < 4; ++c) {
          const bool valid = (j0 + jt * 16 + quad * 4 + c) < N_;
#pragma unroll
          for (int rt = 0; rt < 2; ++rt)
            if (!valid) s[rt][jt][c] = -1e30f;
        }
    }

    // ---- static softmax in-register; pack to PV A-frags via v_perm ----
    v4s pa[2][4];
#pragma unroll
    for (int rt = 0; rt < 2; ++rt)
#pragma unroll
      for (int jt = 0; jt < 4; ++jt) {
        float p0 = fexp2(s[rt][jt][0]);
        float p1 = fexp2(s[rt][jt][1]);
        float p2 = fexp2(s[rt][jt][2]);
        float p3 = fexp2(s[rt][jt][3]);
        const unsigned lo = __builtin_amdgcn_perm(__float_as_uint(p1), __float_as_uint(p0), 0x07060302u);
        const unsigned hi = __builtin_amdgcn_perm(__float_as_uint(p3), __float_as_uint(p2), 0x07060302u);
        v4s pv;
        ((unsigned*)&pv)[0] = lo;
        ((unsigned*)&pv)[1] = hi;
        pa[rt][jt] = pv;
      }

    // ---- PV: K=16 MFMAs, A from registers, B (V) from LDS b64 ----
#pragma unroll
    for (int jt = 0; jt < 4; ++jt) {
      v4s vf[4];
#pragma unroll
      for (int nt = 0; nt < 4; ++nt) {
        const int d  = nt * 16 + l15;
        const int pc = (jt * 2 + (quad >> 1)) ^ (d & 7);   // physical 16B chunk
        vf[nt] = *(const v4s*)&Vs[p][d * 64 + pc * 8 + (quad & 1) * 4];
      }
#pragma unroll
      for (int rt = 0; rt < 2; ++rt) {
        ol[rt] = __builtin_amdgcn_mfma_f32_16x16x16bf16_1k(pa[rt][jt], ones, ol[rt], 0, 0, 0);
#pragma unroll
        for (int nt = 0; nt < 4; ++nt)
          o[rt][nt] = __builtin_amdgcn_mfma_f32_16x16x16bf16_1k(pa[rt][jt], vf[nt], o[rt][nt], 0, 0, 0);
      }
    }
  }

  // ---- epilogue: denominator already in correct lane slots ----
#pragma unroll
  for (int rt = 0; rt < 2; ++rt) {
#pragma unroll
    for (int c = 0; c < 4; ++c) {
      const int row = i0 + wr * 32 + rt * 16 + quad * 4 + c;
      const float rl = 1.0f / ol[rt][c];
#pragma unroll
      for (int nt = 0; nt < 4; ++nt)
        Y[(size_t)(b * N_ + row) * D_ + (bh & 15) * 64 + nt * 16 + l15] = f2bf(o[rt][nt][c] * rl);
    }
  }
}

// ---------------- attention for the single tail q-row (row 1024) ----------
// 1 wave per (b,h). Phase 1: lane j' = it*64+lane computes s, p -> LDS.
// Phase 2: lane d accumulates o_d = sum_j P[j] * V[d][j] (vt is [d][j]).
__global__ __launch_bounds__(64) void k_attn_row(const unsigned short* __restrict__ qt,
                                                 const unsigned short* __restrict__ kt,
                                                 const unsigned short* __restrict__ vt,
                                                 const float* __restrict__ Bbias,
                                                 unsigned short* __restrict__ Y)
{
  const int bh   = blockIdx.x;
  const int b    = bh >> 4;
  const int h    = bh & 15;
  const int lane = threadIdx.x;
  constexpr int R = N_ - 1;   // 1024

  __shared__ float Qs[64];
  __shared__ float P[NP_];

  Qs[lane] = bf2f(qt[((size_t)bh * NP_ + R) * 64 + lane]);
  __syncthreads();

  const float bmv = Bbias[(size_t)R * N_ + R - 1] * LOG2E;
  const unsigned short* ktb = kt + (size_t)bh * NP_ * 64;

  float lsum = 0.f;
#pragma unroll
  for (int it = 0; it < 17; ++it) {
    const int j = it * 64 + lane;
    const v8s* kr = (const v8s*)(ktb + (size_t)j * 64);
    float s = 0.f;
#pragma unroll
    for (int c = 0; c < 8; ++c) {
      const v8s kv = kr[c];
#pragma unroll
      for (int e = 0; e < 8; ++e)
        s += Qs[c * 8 + e] * bf2f((unsigned short)kv[e]);
    }
    if (j == R - 1) s += bmv;
    float p = (j < N_) ? fexp2(s) : 0.f;
    P[j] = p;
    lsum += p;
  }
  const float linv = 1.0f / wave_sum64(lsum);
  __syncthreads();

  const unsigned short* vr = vt + ((size_t)bh * 64 + lane) * NP_;
  float o = 0.f;
#pragma unroll
  for (int it = 0; it < 136; ++it) {   // 1088 / 8
    const v8s vv = *(const v8s*)(vr + it * 8);
#pragma unroll
    for (int e = 0; e < 8; ++e)
      o += P[it * 8 + e] * bf2f((unsigned short)vv[e]);
  }
  Y[(size_t)(b * N_ + R) * D_ + h * 64 + lane] = f2bf(o * linv);
}

extern "C" void kernel_launch(void* const* d_in, const int* in_sizes, int n_in,
                              void* d_out, int out_size, void* d_ws, size_t ws_size,
                              hipStream_t stream)
{
  const float* x      = (const float*)d_in[0];
  const float* fc     = (const float*)d_in[1];
  const float* g      = (const float*)d_in[2];
  const float* qkv_w  = (const float*)d_in[3];
  const float* qkv_b  = (const float*)d_in[4];
  const float* out_w  = (const float*)d_in[5];
  const float* out_b  = (const float*)d_in[6];
  const float* gate_w = (const float*)d_in[7];
  const float* gate_b = (const float*)d_in[8];
  const float* Bbias  = (const float*)d_in[9];
  float* out = (float*)d_out;

  // workspace (~182 MB)
  float* qkv = (float*)d_ws;                                   // M_*3072 f32
  float* zo  = qkv;                                            // alias (valid after attn)
  unsigned short* ybf = (unsigned short*)(qkv + (size_t)M_ * D_);  // alias: dead qkv mid-region
  unsigned short* qt      = (unsigned short*)(qkv + (size_t)M_ * K3_);  // 128*NP_*64
  unsigned short* kt      = qt + (size_t)128 * NP_ * 64;
  unsigned short* vt      = kt + (size_t)128 * NP_ * 64;
  unsigned short* qkvw_bf = vt + (size_t)128 * NP_ * 64;       // 3072*1024
  unsigned short* wo_bf   = qkvw_bf + (size_t)K3_ * D_;        // 1024*1024
  unsigned short* wg_bf   = wo_bf + (size_t)D_ * D_;           // 1024*1024
  unsigned short* hbf     = wg_bf + (size_t)D_ * D_;           // M_*1024

  // 0. weight conversion to bf16 (single launch)
  k_f2bf_all<<<(K3_ * D_ + 2 * D_ * D_) / 1024, 256, 0, stream>>>(
      qkv_w, out_w, gate_w, qkvw_bf, wo_bf, wg_bf);

  // 1. zero-centered RMSNorm -> bf16
  k_rmsnorm<<<M_, 256, 0, stream>>>(x, g, hbf);

  // 2. qkv projection (256x256 pipelined bf16 MFMA) -> f32 qkv
  dim3 g1(K3_ / 256, (M_ + 255) / 256);        // (12, 33)
  k_gemm256<0><<<g1, 512, 0, stream>>>(hbf, qkvw_bf, qkv_b, qkv, nullptr, nullptr, M_, K3_, D_);

  // 3. Q/K rope + Q/K/V bf16 repack
  dim3 gv_(B_ * H_, NP_ / 64);                 // (128, 17)
  k_repack_qkv<<<gv_, 256, 0, stream>>>(qkv, fc, qt, kt, vt);

  // 4. attention: rows 0..1023 (MFMA) + row 1024 (1-wave tail kernel)
  dim3 g2(B_ * H_, 8);                         // (128, 8)
  k_attn_mfma<<<g2, 256, 0, stream>>>(qt, kt, vt, Bbias, ybf);
  k_attn_row<<<B_ * H_, 64, 0, stream>>>(qt, kt, vt, Bbias, ybf);

  // 5. out projection: zo = y @ out_w.T + out_b
  dim3 g3(D_ / 256, (M_ + 255) / 256);         // (4, 33)
  k_gemm256<0><<<g3, 512, 0, stream>>>(ybf, wo_bf, out_b, zo, nullptr, nullptr, M_, D_, D_);

  // 6. gate projection + sigmoid-gate + residual
  k_gemm256<1><<<g3, 512, 0, stream>>>(hbf, wg_bf, gate_b, out, zo, x, M_, D_, D_);
}

// Round 5
// 399.349 us; speedup vs baseline: 1.0541x; 1.0541x over previous
//
#include <hip/hip_runtime.h>
#include <math.h>

constexpr int B_  = 8;
constexpr int N_  = 1025;
constexpr int D_  = 1024;
constexpr int H_  = 16;
constexpr int M_  = B_ * N_;   // 8200 rows
constexpr int K3_ = 3 * D_;    // 3072
constexpr int NP_ = 1088;      // padded key count (17 * 64)

constexpr float LOG2E = 1.4426950408889634f;

typedef short  v8s __attribute__((ext_vector_type(8)));
typedef short  v4s __attribute__((ext_vector_type(4)));
typedef float  v4f __attribute__((ext_vector_type(4)));

__device__ __forceinline__ float wave_sum64(float v) {
#pragma unroll
  for (int o = 32; o; o >>= 1) v += __shfl_xor(v, o, 64);
  return v;
}

__device__ __forceinline__ unsigned short f2bf(float f) {
  unsigned u = __float_as_uint(f);
  u += 0x7FFFu + ((u >> 16) & 1u);
  return (unsigned short)(u >> 16);
}

__device__ __forceinline__ float bf2f(unsigned short s) {
  return __uint_as_float(((unsigned)s) << 16);
}

// raw v_exp_f32: computes 2^x (no base-conversion mul)
__device__ __forceinline__ float fexp2(float x) {
  float r;
  asm("v_exp_f32 %0, %1" : "=v"(r) : "v"(x));
  return r;
}

// async 16B global -> LDS (wave-uniform lds base + lane*16; global addr per-lane)
__device__ __forceinline__ void gload16(const unsigned short* g, unsigned short* l) {
  __builtin_amdgcn_global_load_lds(
      (const __attribute__((address_space(1))) unsigned int*)g,
      (__attribute__((address_space(3))) unsigned int*)l, 16, 0, 0);
}

// ---------------- fp32 -> bf16 convert (all 3 weight mats, 1 launch) --------
__global__ __launch_bounds__(256) void k_f2bf_all(const float* __restrict__ w0,
                                                  const float* __restrict__ w1,
                                                  const float* __restrict__ w2,
                                                  unsigned short* __restrict__ d0,
                                                  unsigned short* __restrict__ d1,
                                                  unsigned short* __restrict__ d2)
{
  const int n0 = K3_ * D_, n1 = D_ * D_;
  int i = (blockIdx.x * 256 + threadIdx.x) * 4;
  const float* s; unsigned short* d;
  if (i < n0)            { s = w0;            d = d0;            }
  else if (i < n0 + n1)  { s = w1; i -= n0;   d = d1;            }
  else                   { s = w2; i -= n0 + n1; d = d2;         }
  const float4 v = *(const float4*)(s + i);
  ushort4 o;
  o.x = f2bf(v.x); o.y = f2bf(v.y); o.z = f2bf(v.z); o.w = f2bf(v.w);
  *(ushort4*)(d + i) = o;
}

// ---------------- zero-centered RMSNorm -> bf16 ----------------
__global__ __launch_bounds__(256) void k_rmsnorm(const float* __restrict__ X,
                                                 const float* __restrict__ gw,
                                                 unsigned short* __restrict__ Hb)
{
  const int m = blockIdx.x;
  const int t = threadIdx.x;
  const int wid = t >> 6, lane = t & 63;
  __shared__ float red[4];

  const float4 v = ((const float4*)(X + (size_t)m * D_))[t];
  float s = wave_sum64(v.x + v.y + v.z + v.w);
  if (lane == 0) red[wid] = s;
  __syncthreads();
  const float mean = (red[0] + red[1] + red[2] + red[3]) * (1.0f / (float)D_);

  const float4 x0 = make_float4(v.x - mean, v.y - mean, v.z - mean, v.w - mean);
  float ss = wave_sum64(x0.x * x0.x + x0.y * x0.y + x0.z * x0.z + x0.w * x0.w);
  __syncthreads();
  if (lane == 0) red[wid] = ss;
  __syncthreads();
  const float inv = rsqrtf((red[0] + red[1] + red[2] + red[3]) * (1.0f / (float)D_) + 1e-8f);

  const float4 gv = ((const float4*)gw)[t];
  ushort4 o;
  o.x = f2bf(x0.x * inv * gv.x);  o.y = f2bf(x0.y * inv * gv.y);
  o.z = f2bf(x0.z * inv * gv.z);  o.w = f2bf(x0.w * inv * gv.w);
  ((ushort4*)(Hb + (size_t)m * D_))[t] = o;
}

// ---------------- 256x256 deep-pipelined bf16 MFMA GEMM ----------------
// 8 waves (2M x 4N, 128x64 out/wave), BK=64, 128KB double-buffered LDS,
// XOR-swizzled chunks, staging 2 K-tiles ahead with counted vmcnt(8),
// quadrant-phase MFMA with s_setprio. NO XCD swizzle (measured -30us, R4).
template<int EPI>
__global__ __launch_bounds__(512, 2) void k_gemm256(
    const unsigned short* __restrict__ A,
    const unsigned short* __restrict__ Wt,
    const float* __restrict__ bias,
    float* __restrict__ C,
    const float* __restrict__ ZO,
    const float* __restrict__ X,
    int Mrows, int Ncols, int K)
{
  __shared__ __align__(16) unsigned short As[2][256 * 64];   // 64 KB
  __shared__ __align__(16) unsigned short Bs[2][256 * 64];   // 64 KB

  const int t    = threadIdx.x;
  const int w    = t >> 6;            // 0..7
  const int lane = t & 63;
  const int l15  = lane & 15;
  const int quad = lane >> 4;
  const int wr   = w >> 2;            // 0..1 (M)
  const int wc   = w & 3;             // 0..3 (N)
  const int m0   = blockIdx.y * 256;
  const int n0   = blockIdx.x * 256;

  const int rl = lane >> 3;           // staging row within 8-row group
  const int cg = (lane & 7) ^ rl;     // pre-swizzled source chunk (involution)

  auto stageA = [&](int bb, int ktile, int h) {
#pragma unroll
    for (int cc = 0; cc < 2; ++cc) {
      const int rt = h * 128 + cc * 64 + w * 8;
      const int gr = min(m0 + rt + rl, Mrows - 1);
      gload16(A + (size_t)gr * K + ktile * 64 + cg * 8, &As[bb][rt * 64]);
    }
  };
  auto stageB = [&](int bb, int ktile, int h) {
#pragma unroll
    for (int cc = 0; cc < 2; ++cc) {
      const int rt = h * 128 + cc * 64 + w * 8;
      gload16(Wt + (size_t)(n0 + rt + rl) * K + ktile * 64 + cg * 8, &Bs[bb][rt * 64]);
    }
  };

  v4f acc[8][4];
#pragma unroll
  for (int i = 0; i < 8; ++i)
#pragma unroll
    for (int j = 0; j < 4; ++j) acc[i][j] = (v4f){0.f, 0.f, 0.f, 0.f};

  const int NT = K >> 6;   // 16 for K=1024

  // prologue: stage tiles 0 and 1 (8 loads/wave each)
  stageA(0, 0, 0); stageA(0, 0, 1); stageB(0, 0, 0); stageB(0, 0, 1);
  stageA(1, 1, 0); stageA(1, 1, 1); stageB(1, 1, 0); stageB(1, 1, 1);

  const int arow = wr * 128;
  const int brow = wc * 64;

  for (int kt = 0; kt < NT; ++kt) {
    const int bb = kt & 1;
    if (kt < NT - 1) asm volatile("s_waitcnt vmcnt(8)" ::: "memory");
    else             asm volatile("s_waitcnt vmcnt(0)" ::: "memory");
    __builtin_amdgcn_s_barrier();

    const bool pf = (kt + 2 < NT);

    // ---- P0: ds_read A rows 0..63 + all B; MFMA quadrant (0,lo) ----
    v8s a[4][2], bq[4][2];
#pragma unroll
    for (int mf = 0; mf < 4; ++mf) {
      const int r = arow + mf * 16 + l15;
#pragma unroll
      for (int kc = 0; kc < 2; ++kc)
        a[mf][kc] = *(const v8s*)&As[bb][r * 64 + (((kc * 4 + quad) ^ (l15 & 7)) * 8)];
    }
#pragma unroll
    for (int nf = 0; nf < 4; ++nf) {
      const int r = brow + nf * 16 + l15;
#pragma unroll
      for (int kc = 0; kc < 2; ++kc)
        bq[nf][kc] = *(const v8s*)&Bs[bb][r * 64 + (((kc * 4 + quad) ^ (l15 & 7)) * 8)];
    }
    asm volatile("s_waitcnt lgkmcnt(0)" ::: "memory");
    __builtin_amdgcn_s_barrier();
    __builtin_amdgcn_s_setprio(1);
#pragma unroll
    for (int mf = 0; mf < 4; ++mf)
#pragma unroll
      for (int nf = 0; nf < 2; ++nf)
#pragma unroll
        for (int kc = 0; kc < 2; ++kc)
          acc[mf][nf] = __builtin_amdgcn_mfma_f32_16x16x32_bf16(a[mf][kc], bq[nf][kc], acc[mf][nf], 0, 0, 0);
    __builtin_amdgcn_s_setprio(0);
    __builtin_amdgcn_s_barrier();

    // ---- P1: prefetch B-half0(kt+2); MFMA quadrant (0,hi) ----
    if (pf) stageB(bb, kt + 2, 0);
    __builtin_amdgcn_s_setprio(1);
#pragma unroll
    for (int mf = 0; mf < 4; ++mf)
#pragma unroll
      for (int nf = 2; nf < 4; ++nf)
#pragma unroll
        for (int kc = 0; kc < 2; ++kc)
          acc[mf][nf] = __builtin_amdgcn_mfma_f32_16x16x32_bf16(a[mf][kc], bq[nf][kc], acc[mf][nf], 0, 0, 0);
    __builtin_amdgcn_s_setprio(0);
    __builtin_amdgcn_s_barrier();

    // ---- P2: ds_read A rows 64..127; prefetch B-half1; MFMA (1,lo) ----
#pragma unroll
    for (int mf = 0; mf < 4; ++mf) {
      const int r = arow + 64 + mf * 16 + l15;
#pragma unroll
      for (int kc = 0; kc < 2; ++kc)
        a[mf][kc] = *(const v8s*)&As[bb][r * 64 + (((kc * 4 + quad) ^ (l15 & 7)) * 8)];
    }
    if (pf) stageB(bb, kt + 2, 1);
    asm volatile("s_waitcnt lgkmcnt(0)" ::: "memory");
    __builtin_amdgcn_s_barrier();
    __builtin_amdgcn_s_setprio(1);
#pragma unroll
    for (int mf = 0; mf < 4; ++mf)
#pragma unroll
      for (int nf = 0; nf < 2; ++nf)
#pragma unroll
        for (int kc = 0; kc < 2; ++kc)
          acc[4 + mf][nf] = __builtin_amdgcn_mfma_f32_16x16x32_bf16(a[mf][kc], bq[nf][kc], acc[4 + mf][nf], 0, 0, 0);
    __builtin_amdgcn_s_setprio(0);
    __builtin_amdgcn_s_barrier();

    // ---- P3: prefetch A halves(kt+2); MFMA quadrant (1,hi) ----
    if (pf) { stageA(bb, kt + 2, 0); stageA(bb, kt + 2, 1); }
    __builtin_amdgcn_s_setprio(1);
#pragma unroll
    for (int mf = 0; mf < 4; ++mf)
#pragma unroll
      for (int nf = 2; nf < 4; ++nf)
#pragma unroll
        for (int kc = 0; kc < 2; ++kc)
          acc[4 + mf][nf] = __builtin_amdgcn_mfma_f32_16x16x32_bf16(a[mf][kc], bq[nf][kc], acc[4 + mf][nf], 0, 0, 0);
    __builtin_amdgcn_s_setprio(0);
  }

  float cb[4];
#pragma unroll
  for (int nf = 0; nf < 4; ++nf) cb[nf] = bias[n0 + brow + nf * 16 + l15];

#pragma unroll
  for (int mf = 0; mf < 8; ++mf) {
    const int rbase = m0 + arow + mf * 16 + quad * 4;
#pragma unroll
    for (int c = 0; c < 4; ++c) {
      const int row = rbase + c;
      if (row < Mrows) {
#pragma unroll
        for (int nf = 0; nf < 4; ++nf) {
          const size_t idx = (size_t)row * Ncols + n0 + brow + nf * 16 + l15;
          if (EPI == 0) {
            C[idx] = acc[mf][nf][c] + cb[nf];
          } else {
            const float zg = acc[mf][nf][c] + cb[nf];
            const float sg = 1.0f / (1.0f + __expf(-zg));
            C[idx] = X[idx] + sg * ZO[idx];
          }
        }
      }
    }
  }
}

// ---------------- fused Q/K rope + Q/K/V bf16 repack ----------------
// Q is pre-scaled by 1/sqrt(Dh) * log2(e) so attention can use raw v_exp_f32.
__global__ __launch_bounds__(256) void k_repack_qkv(const float* __restrict__ qkv,
                                                    const float* __restrict__ fc,
                                                    unsigned short* __restrict__ qt,
                                                    unsigned short* __restrict__ kt,
                                                    unsigned short* __restrict__ vt)
{
  const int bh = blockIdx.x;
  const int b  = bh >> 4;
  const int h  = bh & 15;
  const int j0 = blockIdx.y * 64;
  const int t  = threadIdx.x;
  __shared__ float T[64][65];

  // ---- Q and K: rope -> [bh][j][d] ----
  {
    const int row  = t >> 2;
    const int dseg = (t & 3) * 16;
    const int n    = j0 + row;
    unsigned short qb[16], kb[16];
    if (n < N_) {
      const float2* qp = (const float2*)(qkv + (size_t)(b * N_ + n) * K3_ + h * 64 + dseg);
      const float2* kp = (const float2*)(qkv + (size_t)(b * N_ + n) * K3_ + 1024 + h * 64 + dseg);
      const float2* fp = (const float2*)fc + (size_t)n * 32 + dseg / 2;
      const float qs = 0.125f * LOG2E;
#pragma unroll
      for (int j = 0; j < 8; ++j) {
        const float2 f  = fp[j];
        const float2 qv = qp[j];
        qb[2 * j]     = f2bf((qv.x * f.x - qv.y * f.y) * qs);
        qb[2 * j + 1] = f2bf((qv.x * f.y + qv.y * f.x) * qs);
        const float2 kv = kp[j];
        kb[2 * j]     = f2bf(kv.x * f.x - kv.y * f.y);
        kb[2 * j + 1] = f2bf(kv.x * f.y + kv.y * f.x);
      }
    } else {
#pragma unroll
      for (int j = 0; j < 16; ++j) { qb[j] = 0; kb[j] = 0; }
    }
    unsigned short* qd = qt + ((size_t)bh * NP_ + j0 + row) * 64 + dseg;
    *(uint4*)qd       = *(uint4*)&qb[0];
    *(uint4*)(qd + 8) = *(uint4*)&qb[8];
    unsigned short* kd = kt + ((size_t)bh * NP_ + j0 + row) * 64 + dseg;
    *(uint4*)kd       = *(uint4*)&kb[0];
    *(uint4*)(kd + 8) = *(uint4*)&kb[8];
  }

  // ---- V: transpose -> vt[bh][d][j] ----
#pragma unroll
  for (int l = 0; l < 4; ++l) {
    const int j  = (t >> 4) + 16 * l;
    const int jg = j0 + j;
    const int d4 = (t & 15) * 4;
    float4 v = make_float4(0.f, 0.f, 0.f, 0.f);
    if (jg < N_) v = *(const float4*)(qkv + (size_t)(b * N_ + jg) * K3_ + 2048 + h * 64 + d4);
    *(float4*)&T[j][d4] = v;
  }
  __syncthreads();
#pragma unroll
  for (int l = 0; l < 4; ++l) {
    const int d  = (t >> 4) + 16 * l;
    const int j4 = (t & 15) * 4;
    ushort4 o;
    o.x = f2bf(T[j4 + 0][d]); o.y = f2bf(T[j4 + 1][d]);
    o.z = f2bf(T[j4 + 2][d]); o.w = f2bf(T[j4 + 3][d]);
    *(ushort4*)(vt + ((size_t)bh * 64 + d) * NP_ + j0 + j4) = o;
  }
}

// ---------------- MFMA flash attention (rows 0..1023) ----------------
// S computed TRANSPOSED (A=K, B=Q): S^T per-lane layout j=quad*4+reg, i=l15
// == A-operand layout of mfma_f32_16x16x16_bf16 -> PV directly from registers.
// Softmax in log2 domain (Q pre-scaled by log2e): bare v_exp_f32.
// Denominator via ones-MFMA (row-sums land in epilogue lane slots).
// 3-buffer LDS pipeline, prefetch depth 2, counted vmcnt(4) (T3/T4):
// each wave stages 4 loads/chunk; steady state = stage(ic)+stage(ic+1) in
// flight; vmcnt(4) waits for stage(ic), leaves stage(ic+1) flying. Prologue
// stages are issued BEFORE Q loads so the counted wait is conservative-safe.
// No launch_bounds cap (R4: cap to 3/CU forced VGPR 84 -> 45MB spill traffic).
__global__ __launch_bounds__(256) void k_attn_mfma(const unsigned short* __restrict__ qt,
                                                   const unsigned short* __restrict__ kt,
                                                   const unsigned short* __restrict__ vt,
                                                   const float* __restrict__ Bbias,
                                                   unsigned short* __restrict__ Y)
{
  const int bh = blockIdx.x;
  const int b  = bh >> 4;
  const int i0 = blockIdx.y * 128;     // 0..896: all rows < 1024 valid
  const int t  = threadIdx.x;
  const int wr = t >> 6;
  const int lane = t & 63;
  const int l15  = lane & 15;
  const int quad = lane >> 4;

  __shared__ __align__(16) unsigned short Ks[3][64 * 64];   // XOR-swizzled [j][d]
  __shared__ __align__(16) unsigned short Vs[3][64 * 64];   // XOR-swizzled [d][j]

  const unsigned short* ktb = kt + (size_t)bh * NP_ * 64;
  const unsigned short* vtb = vt + (size_t)bh * 64 * NP_;
  const int rw0  = i0 + wr * 32;
  const int rowl = lane >> 3;          // 0..7
  const int lc   = (lane & 7) ^ rowl;  // XOR swizzle (16B chunk granularity)

  auto stage = [&](int ic, int pp) {
    const int js = ic * 64;
    gload16(ktb + (size_t)(js + wr * 16 + rowl) * 64 + lc * 8,      &Ks[pp][(wr * 16) * 64]);
    gload16(ktb + (size_t)(js + wr * 16 + 8 + rowl) * 64 + lc * 8,  &Ks[pp][(wr * 16 + 8) * 64]);
    gload16(vtb + (size_t)(wr * 16 + rowl) * NP_ + js + lc * 8,     &Vs[pp][(wr * 16) * 64]);
    gload16(vtb + (size_t)(wr * 16 + 8 + rowl) * NP_ + js + lc * 8, &Vs[pp][(wr * 16 + 8) * 64]);
  };

  // prologue: prefetch chunks 0 and 1 (issued before any other vmem op)
  stage(0, 0);
  stage(1, 1);

  // ---- Q fragments (B-operand; pre-scaled by 1/8 * log2e) ----
  v8s qf[2][2];
#pragma unroll
  for (int rt = 0; rt < 2; ++rt)
#pragma unroll
    for (int ks = 0; ks < 2; ++ks) {
      const int row = i0 + wr * 32 + rt * 16 + l15;
      qf[rt][ks] = *(const v8s*)(qt + ((size_t)bh * NP_ + row) * 64 + ks * 32 + quad * 8);
    }

  // ---- per-lane tridiagonal bias, pre-scaled to log2 domain ----
  int   rowi[2];
  float bm[2], bp[2];
#pragma unroll
  for (int rt = 0; rt < 2; ++rt) {
    const int r = i0 + wr * 32 + rt * 16 + l15;
    rowi[rt] = r;
    bm[rt] = (r > 0) ? Bbias[(size_t)r * N_ + r - 1] * LOG2E : 0.f;
    bp[rt] = Bbias[(size_t)r * N_ + r + 1] * LOG2E;   // r <= 1023 < N_-1 always
  }

  v4f o[2][4];
  v4f ol[2];   // softmax denominator accumulators (row-sums via ones-MFMA)
#pragma unroll
  for (int rt = 0; rt < 2; ++rt) {
    ol[rt] = (v4f){0.f, 0.f, 0.f, 0.f};
#pragma unroll
    for (int nt = 0; nt < 4; ++nt) o[rt][nt] = (v4f){0.f, 0.f, 0.f, 0.f};
  }
  const v4s ones = { (short)0x3F80, (short)0x3F80, (short)0x3F80, (short)0x3F80 };

  for (int ic = 0; ic < 17; ++ic) {
    const int j0 = ic * 64;
    const int p  = ic % 3;
    // wait for chunk ic's 4 loads; allow chunk ic+1's 4 to stay in flight
    if (ic < 16) asm volatile("s_waitcnt vmcnt(4)" ::: "memory");
    else         asm volatile("s_waitcnt vmcnt(0)" ::: "memory");
    __syncthreads();
    if (ic + 2 <= 16) stage(ic + 2, (ic + 2) % 3);   // depth-2 prefetch

    // ---- QK^T transposed: S^T[j][i] (already in log2 domain) ----
    v4f s[2][4];
#pragma unroll
    for (int jt = 0; jt < 4; ++jt) {
      const int rr  = jt * 16 + l15;
      const v8s kf0 = *(const v8s*)&Ks[p][rr * 64 + ((0 + quad) ^ (rr & 7)) * 8];
      const v8s kf1 = *(const v8s*)&Ks[p][rr * 64 + ((4 + quad) ^ (rr & 7)) * 8];
#pragma unroll
      for (int rt = 0; rt < 2; ++rt) {
        v4f acc = (v4f){0.f, 0.f, 0.f, 0.f};
        acc = __builtin_amdgcn_mfma_f32_16x16x32_bf16(kf0, qf[rt][0], acc, 0, 0, 0);
        acc = __builtin_amdgcn_mfma_f32_16x16x32_bf16(kf1, qf[rt][1], acc, 0, 0, 0);
        s[rt][jt] = acc;
      }
    }

    // ---- sparse tridiagonal bias (wave-uniform rare branch) ----
    if (j0 <= rw0 + 32 && j0 + 64 >= rw0) {
#pragma unroll
      for (int rt = 0; rt < 2; ++rt) {
        const int r = rowi[rt];
#pragma unroll
        for (int jt = 0; jt < 4; ++jt)
#pragma unroll
          for (int c = 0; c < 4; ++c) {
            const int j = j0 + jt * 16 + quad * 4 + c;
            float v = s[rt][jt][c];
            v += (j == r - 1) ? bm[rt] : 0.f;
            v += (j == r + 1) ? bp[rt] : 0.f;
            s[rt][jt][c] = v;
          }
      }
    }
    // ---- key mask (final chunk: padded j rows) ----
    if (ic == 16) {
#pragma unroll
      for (int jt = 0; jt < 4; ++jt)
#pragma unroll
        for (int c = 0; c < 4; ++c) {
          const bool valid = (j0 + jt * 16 + quad * 4 + c) < N_;
#pragma unroll
          for (int rt = 0; rt < 2; ++rt)
            if (!valid) s[rt][jt][c] = -1e30f;
        }
    }

    // ---- static softmax in-register; pack to PV A-frags via v_perm ----
    v4s pa[2][4];
#pragma unroll
    for (int rt = 0; rt < 2; ++rt)
#pragma unroll
      for (int jt = 0; jt < 4; ++jt) {
        float p0 = fexp2(s[rt][jt][0]);
        float p1 = fexp2(s[rt][jt][1]);
        float p2 = fexp2(s[rt][jt][2]);
        float p3 = fexp2(s[rt][jt][3]);
        const unsigned lo = __builtin_amdgcn_perm(__float_as_uint(p1), __float_as_uint(p0), 0x07060302u);
        const unsigned hi = __builtin_amdgcn_perm(__float_as_uint(p3), __float_as_uint(p2), 0x07060302u);
        v4s pv;
        ((unsigned*)&pv)[0] = lo;
        ((unsigned*)&pv)[1] = hi;
        pa[rt][jt] = pv;
      }

    // ---- PV: K=16 MFMAs, A from registers, B (V) from LDS b64 ----
#pragma unroll
    for (int jt = 0; jt < 4; ++jt) {
      v4s vf[4];
#pragma unroll
      for (int nt = 0; nt < 4; ++nt) {
        const int d  = nt * 16 + l15;
        const int pc = (jt * 2 + (quad >> 1)) ^ (d & 7);   // physical 16B chunk
        vf[nt] = *(const v4s*)&Vs[p][d * 64 + pc * 8 + (quad & 1) * 4];
      }
#pragma unroll
      for (int rt = 0; rt < 2; ++rt) {
        ol[rt] = __builtin_amdgcn_mfma_f32_16x16x16bf16_1k(pa[rt][jt], ones, ol[rt], 0, 0, 0);
#pragma unroll
        for (int nt = 0; nt < 4; ++nt)
          o[rt][nt] = __builtin_amdgcn_mfma_f32_16x16x16bf16_1k(pa[rt][jt], vf[nt], o[rt][nt], 0, 0, 0);
      }
    }
  }

  // ---- epilogue: denominator already in correct lane slots ----
#pragma unroll
  for (int rt = 0; rt < 2; ++rt) {
#pragma unroll
    for (int c = 0; c < 4; ++c) {
      const int row = i0 + wr * 32 + rt * 16 + quad * 4 + c;
      const float rl = 1.0f / ol[rt][c];
#pragma unroll
      for (int nt = 0; nt < 4; ++nt)
        Y[(size_t)(b * N_ + row) * D_ + (bh & 15) * 64 + nt * 16 + l15] = f2bf(o[rt][nt][c] * rl);
    }
  }
}

// ---------------- attention for the single tail q-row (row 1024) ----------
__global__ __launch_bounds__(64) void k_attn_row(const unsigned short* __restrict__ qt,
                                                 const unsigned short* __restrict__ kt,
                                                 const unsigned short* __restrict__ vt,
                                                 const float* __restrict__ Bbias,
                                                 unsigned short* __restrict__ Y)
{
  const int bh   = blockIdx.x;
  const int b    = bh >> 4;
  const int h    = bh & 15;
  const int lane = threadIdx.x;
  constexpr int R = N_ - 1;   // 1024

  __shared__ float Qs[64];
  __shared__ float P[NP_];

  Qs[lane] = bf2f(qt[((size_t)bh * NP_ + R) * 64 + lane]);
  __syncthreads();

  const float bmv = Bbias[(size_t)R * N_ + R - 1] * LOG2E;
  const unsigned short* ktb = kt + (size_t)bh * NP_ * 64;

  float lsum = 0.f;
#pragma unroll
  for (int it = 0; it < 17; ++it) {
    const int j = it * 64 + lane;
    const v8s* kr = (const v8s*)(ktb + (size_t)j * 64);
    float s = 0.f;
#pragma unroll
    for (int c = 0; c < 8; ++c) {
      const v8s kv = kr[c];
#pragma unroll
      for (int e = 0; e < 8; ++e)
        s += Qs[c * 8 + e] * bf2f((unsigned short)kv[e]);
    }
    if (j == R - 1) s += bmv;
    float p = (j < N_) ? fexp2(s) : 0.f;
    P[j] = p;
    lsum += p;
  }
  const float linv = 1.0f / wave_sum64(lsum);
  __syncthreads();

  const unsigned short* vr = vt + ((size_t)bh * 64 + lane) * NP_;
  float o = 0.f;
#pragma unroll
  for (int it = 0; it < 136; ++it) {   // 1088 / 8
    const v8s vv = *(const v8s*)(vr + it * 8);
#pragma unroll
    for (int e = 0; e < 8; ++e)
      o += P[it * 8 + e] * bf2f((unsigned short)vv[e]);
  }
  Y[(size_t)(b * N_ + R) * D_ + h * 64 + lane] = f2bf(o * linv);
}

extern "C" void kernel_launch(void* const* d_in, const int* in_sizes, int n_in,
                              void* d_out, int out_size, void* d_ws, size_t ws_size,
                              hipStream_t stream)
{
  const float* x      = (const float*)d_in[0];
  const float* fc     = (const float*)d_in[1];
  const float* g      = (const float*)d_in[2];
  const float* qkv_w  = (const float*)d_in[3];
  const float* qkv_b  = (const float*)d_in[4];
  const float* out_w  = (const float*)d_in[5];
  const float* out_b  = (const float*)d_in[6];
  const float* gate_w = (const float*)d_in[7];
  const float* gate_b = (const float*)d_in[8];
  const float* Bbias  = (const float*)d_in[9];
  float* out = (float*)d_out;

  // workspace (~182 MB)
  float* qkv = (float*)d_ws;                                   // M_*3072 f32
  float* zo  = qkv;                                            // alias (valid after attn)
  unsigned short* ybf = (unsigned short*)(qkv + (size_t)M_ * D_);  // alias: dead qkv mid-region
  unsigned short* qt      = (unsigned short*)(qkv + (size_t)M_ * K3_);  // 128*NP_*64
  unsigned short* kt      = qt + (size_t)128 * NP_ * 64;
  unsigned short* vt      = kt + (size_t)128 * NP_ * 64;
  unsigned short* qkvw_bf = vt + (size_t)128 * NP_ * 64;       // 3072*1024
  unsigned short* wo_bf   = qkvw_bf + (size_t)K3_ * D_;        // 1024*1024
  unsigned short* wg_bf   = wo_bf + (size_t)D_ * D_;           // 1024*1024
  unsigned short* hbf     = wg_bf + (size_t)D_ * D_;           // M_*1024

  // 0. weight conversion to bf16 (single launch)
  k_f2bf_all<<<(K3_ * D_ + 2 * D_ * D_) / 1024, 256, 0, stream>>>(
      qkv_w, out_w, gate_w, qkvw_bf, wo_bf, wg_bf);

  // 1. zero-centered RMSNorm -> bf16
  k_rmsnorm<<<M_, 256, 0, stream>>>(x, g, hbf);

  // 2. qkv projection (256x256 pipelined bf16 MFMA) -> f32 qkv
  dim3 g1(K3_ / 256, (M_ + 255) / 256);        // (12, 33)
  k_gemm256<0><<<g1, 512, 0, stream>>>(hbf, qkvw_bf, qkv_b, qkv, nullptr, nullptr, M_, K3_, D_);

  // 3. Q/K rope + Q/K/V bf16 repack
  dim3 gv_(B_ * H_, NP_ / 64);                 // (128, 17)
  k_repack_qkv<<<gv_, 256, 0, stream>>>(qkv, fc, qt, kt, vt);

  // 4. attention: rows 0..1023 (MFMA) + row 1024 (1-wave tail kernel)
  dim3 g2(B_ * H_, 8);                         // (128, 8)
  k_attn_mfma<<<g2, 256, 0, stream>>>(qt, kt, vt, Bbias, ybf);
  k_attn_row<<<B_ * H_, 64, 0, stream>>>(qt, kt, vt, Bbias, ybf);

  // 5. out projection: zo = y @ out_w.T + out_b
  dim3 g3(D_ / 256, (M_ + 255) / 256);         // (4, 33)
  k_gemm256<0><<<g3, 512, 0, stream>>>(ybf, wo_bf, out_b, zo, nullptr, nullptr, M_, D_, D_);

  // 6. gate projection + sigmoid-gate + residual
  k_gemm256<1><<<g3, 512, 0, stream>>>(hbf, wg_bf, gate_b, out, zo, x, M_, D_, D_);
}

// Round 6
// 376.094 us; speedup vs baseline: 1.1193x; 1.0618x over previous
//
#include <hip/hip_runtime.h>
#include <math.h>

constexpr int B_  = 8;
constexpr int N_  = 1025;
constexpr int D_  = 1024;
constexpr int H_  = 16;
constexpr int M_  = B_ * N_;   // 8200 rows
constexpr int K3_ = 3 * D_;    // 3072
constexpr int NP_ = 1088;      // padded key count (17 * 64)

constexpr float LOG2E = 1.4426950408889634f;

typedef short  v8s __attribute__((ext_vector_type(8)));
typedef short  v4s __attribute__((ext_vector_type(4)));
typedef float  v4f __attribute__((ext_vector_type(4)));

__device__ __forceinline__ float wave_sum64(float v) {
#pragma unroll
  for (int o = 32; o; o >>= 1) v += __shfl_xor(v, o, 64);
  return v;
}

__device__ __forceinline__ unsigned short f2bf(float f) {
  unsigned u = __float_as_uint(f);
  u += 0x7FFFu + ((u >> 16) & 1u);
  return (unsigned short)(u >> 16);
}

__device__ __forceinline__ float bf2f(unsigned short s) {
  return __uint_as_float(((unsigned)s) << 16);
}

// raw v_exp_f32: computes 2^x (no base-conversion mul)
__device__ __forceinline__ float fexp2(float x) {
  float r;
  asm("v_exp_f32 %0, %1" : "=v"(r) : "v"(x));
  return r;
}

// async 16B global -> LDS (wave-uniform lds base + lane*16; global addr per-lane)
__device__ __forceinline__ void gload16(const unsigned short* g, unsigned short* l) {
  __builtin_amdgcn_global_load_lds(
      (const __attribute__((address_space(1))) unsigned int*)g,
      (__attribute__((address_space(3))) unsigned int*)l, 16, 0, 0);
}

// ---------------- fp32 -> bf16 convert (all 3 weight mats, 1 launch) --------
__global__ __launch_bounds__(256) void k_f2bf_all(const float* __restrict__ w0,
                                                  const float* __restrict__ w1,
                                                  const float* __restrict__ w2,
                                                  unsigned short* __restrict__ d0,
                                                  unsigned short* __restrict__ d1,
                                                  unsigned short* __restrict__ d2)
{
  const int n0 = K3_ * D_, n1 = D_ * D_;
  int i = (blockIdx.x * 256 + threadIdx.x) * 4;
  const float* s; unsigned short* d;
  if (i < n0)            { s = w0;            d = d0;            }
  else if (i < n0 + n1)  { s = w1; i -= n0;   d = d1;            }
  else                   { s = w2; i -= n0 + n1; d = d2;         }
  const float4 v = *(const float4*)(s + i);
  ushort4 o;
  o.x = f2bf(v.x); o.y = f2bf(v.y); o.z = f2bf(v.z); o.w = f2bf(v.w);
  *(ushort4*)(d + i) = o;
}

// ---------------- zero-centered RMSNorm -> bf16 ----------------
__global__ __launch_bounds__(256) void k_rmsnorm(const float* __restrict__ X,
                                                 const float* __restrict__ gw,
                                                 unsigned short* __restrict__ Hb)
{
  const int m = blockIdx.x;
  const int t = threadIdx.x;
  const int wid = t >> 6, lane = t & 63;
  __shared__ float red[4];

  const float4 v = ((const float4*)(X + (size_t)m * D_))[t];
  float s = wave_sum64(v.x + v.y + v.z + v.w);
  if (lane == 0) red[wid] = s;
  __syncthreads();
  const float mean = (red[0] + red[1] + red[2] + red[3]) * (1.0f / (float)D_);

  const float4 x0 = make_float4(v.x - mean, v.y - mean, v.z - mean, v.w - mean);
  float ss = wave_sum64(x0.x * x0.x + x0.y * x0.y + x0.z * x0.z + x0.w * x0.w);
  __syncthreads();
  if (lane == 0) red[wid] = ss;
  __syncthreads();
  const float inv = rsqrtf((red[0] + red[1] + red[2] + red[3]) * (1.0f / (float)D_) + 1e-8f);

  const float4 gv = ((const float4*)gw)[t];
  ushort4 o;
  o.x = f2bf(x0.x * inv * gv.x);  o.y = f2bf(x0.y * inv * gv.y);
  o.z = f2bf(x0.z * inv * gv.z);  o.w = f2bf(x0.w * inv * gv.w);
  ((ushort4*)(Hb + (size_t)m * D_))[t] = o;
}

// ---------------- 256x256 deep-pipelined bf16 MFMA GEMM (QKV, bf16 out) -----
// 8 waves (2M x 4N, 128x64 out/wave), BK=64, 128KB double-buffered LDS,
// XOR-swizzled chunks, staging 2 K-tiles ahead with counted vmcnt(8),
// quadrant-phase MFMA with s_setprio. Output written bf16 (halves WRITE).
__global__ __launch_bounds__(512, 2) void k_gemm_qkv(
    const unsigned short* __restrict__ A,
    const unsigned short* __restrict__ Wt,
    const float* __restrict__ bias,
    unsigned short* __restrict__ Cb,
    int Mrows, int Ncols, int K)
{
  __shared__ __align__(16) unsigned short As[2][256 * 64];   // 64 KB
  __shared__ __align__(16) unsigned short Bs[2][256 * 64];   // 64 KB

  const int t    = threadIdx.x;
  const int w    = t >> 6;            // 0..7
  const int lane = t & 63;
  const int l15  = lane & 15;
  const int quad = lane >> 4;
  const int wr   = w >> 2;            // 0..1 (M)
  const int wc   = w & 3;             // 0..3 (N)
  const int m0   = blockIdx.y * 256;
  const int n0   = blockIdx.x * 256;

  const int rl = lane >> 3;           // staging row within 8-row group
  const int cg = (lane & 7) ^ rl;     // pre-swizzled source chunk (involution)

  auto stageA = [&](int bb, int ktile, int h) {
#pragma unroll
    for (int cc = 0; cc < 2; ++cc) {
      const int rt = h * 128 + cc * 64 + w * 8;
      const int gr = min(m0 + rt + rl, Mrows - 1);
      gload16(A + (size_t)gr * K + ktile * 64 + cg * 8, &As[bb][rt * 64]);
    }
  };
  auto stageB = [&](int bb, int ktile, int h) {
#pragma unroll
    for (int cc = 0; cc < 2; ++cc) {
      const int rt = h * 128 + cc * 64 + w * 8;
      gload16(Wt + (size_t)(n0 + rt + rl) * K + ktile * 64 + cg * 8, &Bs[bb][rt * 64]);
    }
  };

  v4f acc[8][4];
#pragma unroll
  for (int i = 0; i < 8; ++i)
#pragma unroll
    for (int j = 0; j < 4; ++j) acc[i][j] = (v4f){0.f, 0.f, 0.f, 0.f};

  const int NT = K >> 6;   // 16 for K=1024

  // prologue: stage tiles 0 and 1 (8 loads/wave each)
  stageA(0, 0, 0); stageA(0, 0, 1); stageB(0, 0, 0); stageB(0, 0, 1);
  stageA(1, 1, 0); stageA(1, 1, 1); stageB(1, 1, 0); stageB(1, 1, 1);

  const int arow = wr * 128;
  const int brow = wc * 64;

  for (int kt = 0; kt < NT; ++kt) {
    const int bb = kt & 1;
    if (kt < NT - 1) asm volatile("s_waitcnt vmcnt(8)" ::: "memory");
    else             asm volatile("s_waitcnt vmcnt(0)" ::: "memory");
    __builtin_amdgcn_s_barrier();

    const bool pf = (kt + 2 < NT);

    // ---- P0: ds_read A rows 0..63 + all B; MFMA quadrant (0,lo) ----
    v8s a[4][2], bq[4][2];
#pragma unroll
    for (int mf = 0; mf < 4; ++mf) {
      const int r = arow + mf * 16 + l15;
#pragma unroll
      for (int kc = 0; kc < 2; ++kc)
        a[mf][kc] = *(const v8s*)&As[bb][r * 64 + (((kc * 4 + quad) ^ (l15 & 7)) * 8)];
    }
#pragma unroll
    for (int nf = 0; nf < 4; ++nf) {
      const int r = brow + nf * 16 + l15;
#pragma unroll
      for (int kc = 0; kc < 2; ++kc)
        bq[nf][kc] = *(const v8s*)&Bs[bb][r * 64 + (((kc * 4 + quad) ^ (l15 & 7)) * 8)];
    }
    asm volatile("s_waitcnt lgkmcnt(0)" ::: "memory");
    __builtin_amdgcn_s_barrier();
    __builtin_amdgcn_s_setprio(1);
#pragma unroll
    for (int mf = 0; mf < 4; ++mf)
#pragma unroll
      for (int nf = 0; nf < 2; ++nf)
#pragma unroll
        for (int kc = 0; kc < 2; ++kc)
          acc[mf][nf] = __builtin_amdgcn_mfma_f32_16x16x32_bf16(a[mf][kc], bq[nf][kc], acc[mf][nf], 0, 0, 0);
    __builtin_amdgcn_s_setprio(0);
    __builtin_amdgcn_s_barrier();

    // ---- P1: prefetch B-half0(kt+2); MFMA quadrant (0,hi) ----
    if (pf) stageB(bb, kt + 2, 0);
    __builtin_amdgcn_s_setprio(1);
#pragma unroll
    for (int mf = 0; mf < 4; ++mf)
#pragma unroll
      for (int nf = 2; nf < 4; ++nf)
#pragma unroll
        for (int kc = 0; kc < 2; ++kc)
          acc[mf][nf] = __builtin_amdgcn_mfma_f32_16x16x32_bf16(a[mf][kc], bq[nf][kc], acc[mf][nf], 0, 0, 0);
    __builtin_amdgcn_s_setprio(0);
    __builtin_amdgcn_s_barrier();

    // ---- P2: ds_read A rows 64..127; prefetch B-half1; MFMA (1,lo) ----
#pragma unroll
    for (int mf = 0; mf < 4; ++mf) {
      const int r = arow + 64 + mf * 16 + l15;
#pragma unroll
      for (int kc = 0; kc < 2; ++kc)
        a[mf][kc] = *(const v8s*)&As[bb][r * 64 + (((kc * 4 + quad) ^ (l15 & 7)) * 8)];
    }
    if (pf) stageB(bb, kt + 2, 1);
    asm volatile("s_waitcnt lgkmcnt(0)" ::: "memory");
    __builtin_amdgcn_s_barrier();
    __builtin_amdgcn_s_setprio(1);
#pragma unroll
    for (int mf = 0; mf < 4; ++mf)
#pragma unroll
      for (int nf = 0; nf < 2; ++nf)
#pragma unroll
        for (int kc = 0; kc < 2; ++kc)
          acc[4 + mf][nf] = __builtin_amdgcn_mfma_f32_16x16x32_bf16(a[mf][kc], bq[nf][kc], acc[4 + mf][nf], 0, 0, 0);
    __builtin_amdgcn_s_setprio(0);
    __builtin_amdgcn_s_barrier();

    // ---- P3: prefetch A halves(kt+2); MFMA quadrant (1,hi) ----
    if (pf) { stageA(bb, kt + 2, 0); stageA(bb, kt + 2, 1); }
    __builtin_amdgcn_s_setprio(1);
#pragma unroll
    for (int mf = 0; mf < 4; ++mf)
#pragma unroll
      for (int nf = 2; nf < 4; ++nf)
#pragma unroll
        for (int kc = 0; kc < 2; ++kc)
          acc[4 + mf][nf] = __builtin_amdgcn_mfma_f32_16x16x32_bf16(a[mf][kc], bq[nf][kc], acc[4 + mf][nf], 0, 0, 0);
    __builtin_amdgcn_s_setprio(0);
  }

  float cb[4];
#pragma unroll
  for (int nf = 0; nf < 4; ++nf) cb[nf] = bias[n0 + brow + nf * 16 + l15];

#pragma unroll
  for (int mf = 0; mf < 8; ++mf) {
    const int rbase = m0 + arow + mf * 16 + quad * 4;
#pragma unroll
    for (int c = 0; c < 4; ++c) {
      const int row = rbase + c;
      if (row < Mrows) {
#pragma unroll
        for (int nf = 0; nf < 4; ++nf)
          Cb[(size_t)row * Ncols + n0 + brow + nf * 16 + l15] = f2bf(acc[mf][nf][c] + cb[nf]);
      }
    }
  }
}

// ---------------- fused dual GEMM: out-proj + gate-proj + gating -----------
// zy = ybf @ wo^T + out_b ; zg = hbf @ wg^T + gate_b ;
// out = x + sigmoid(zg) * zy   -- all in registers, no zo round-trip.
// BM=BN=128, BK=64, 8 waves (64x32 per wave per gemm), 128KB LDS (4 streams
// x 2 buffers x 32KB/2... = 4x32KB), counted vmcnt(8) depth-2 prefetch.
// Per tile: half1 {read a1/b1, lgkm+bar, stage1(kt+2), 16 MFMA}, then
// half2 identically for gemm2. 8 loads/wave/tile total -> vmcnt(8).
__global__ __launch_bounds__(512, 2) void k_gemm_outgate(
    const unsigned short* __restrict__ A1,   // ybf
    const unsigned short* __restrict__ A2,   // hbf
    const unsigned short* __restrict__ W1,   // wo_bf  [n][k]
    const unsigned short* __restrict__ W2,   // wg_bf  [n][k]
    const float* __restrict__ b1v,
    const float* __restrict__ b2v,
    const float* __restrict__ X,
    float* __restrict__ Cout,
    int Mrows)
{
  constexpr int K = 1024;
  constexpr int Ncols = 1024;
  __shared__ __align__(16) unsigned short As1[2][128 * 64];  // 32 KB
  __shared__ __align__(16) unsigned short Bs1[2][128 * 64];  // 32 KB
  __shared__ __align__(16) unsigned short As2[2][128 * 64];  // 32 KB
  __shared__ __align__(16) unsigned short Bs2[2][128 * 64];  // 32 KB

  const int t    = threadIdx.x;
  const int w    = t >> 6;            // 0..7
  const int lane = t & 63;
  const int l15  = lane & 15;
  const int quad = lane >> 4;
  const int wr   = w >> 2;            // 0..1 (M)
  const int wc   = w & 3;             // 0..3 (N)
  const int m0   = blockIdx.y * 128;
  const int n0   = blockIdx.x * 128;

  const int rl = lane >> 3;
  const int cg = (lane & 7) ^ rl;

  auto stage1 = [&](int bb, int ktile) {
#pragma unroll
    for (int cc = 0; cc < 2; ++cc) {
      const int rt = cc * 64 + w * 8;
      const int gr = min(m0 + rt + rl, Mrows - 1);
      gload16(A1 + (size_t)gr * K + ktile * 64 + cg * 8, &As1[bb][rt * 64]);
      gload16(W1 + (size_t)(n0 + rt + rl) * K + ktile * 64 + cg * 8, &Bs1[bb][rt * 64]);
    }
  };
  auto stage2 = [&](int bb, int ktile) {
#pragma unroll
    for (int cc = 0; cc < 2; ++cc) {
      const int rt = cc * 64 + w * 8;
      const int gr = min(m0 + rt + rl, Mrows - 1);
      gload16(A2 + (size_t)gr * K + ktile * 64 + cg * 8, &As2[bb][rt * 64]);
      gload16(W2 + (size_t)(n0 + rt + rl) * K + ktile * 64 + cg * 8, &Bs2[bb][rt * 64]);
    }
  };

  v4f acc1[4][2], acc2[4][2];
#pragma unroll
  for (int i = 0; i < 4; ++i)
#pragma unroll
    for (int j = 0; j < 2; ++j) {
      acc1[i][j] = (v4f){0.f, 0.f, 0.f, 0.f};
      acc2[i][j] = (v4f){0.f, 0.f, 0.f, 0.f};
    }

  // prologue: tiles 0 and 1 for both gemms (16 loads/wave in flight)
  stage1(0, 0); stage2(0, 0);
  stage1(1, 1); stage2(1, 1);

  const int arow = wr * 64;
  const int brow = wc * 32;
  constexpr int NT = K >> 6;   // 16

  for (int kt = 0; kt < NT; ++kt) {
    const int bb = kt & 1;
    if (kt < NT - 1) asm volatile("s_waitcnt vmcnt(8)" ::: "memory");
    else             asm volatile("s_waitcnt vmcnt(0)" ::: "memory");
    __builtin_amdgcn_s_barrier();
    const bool pf = (kt + 2 < NT);

    // ---- half 1: gemm1 ----
    {
      v8s a[4][2], bq[2][2];
#pragma unroll
      for (int mf = 0; mf < 4; ++mf) {
        const int r = arow + mf * 16 + l15;
#pragma unroll
        for (int kc = 0; kc < 2; ++kc)
          a[mf][kc] = *(const v8s*)&As1[bb][r * 64 + (((kc * 4 + quad) ^ (l15 & 7)) * 8)];
      }
#pragma unroll
      for (int nf = 0; nf < 2; ++nf) {
        const int r = brow + nf * 16 + l15;
#pragma unroll
        for (int kc = 0; kc < 2; ++kc)
          bq[nf][kc] = *(const v8s*)&Bs1[bb][r * 64 + (((kc * 4 + quad) ^ (l15 & 7)) * 8)];
      }
      asm volatile("s_waitcnt lgkmcnt(0)" ::: "memory");
      __builtin_amdgcn_s_barrier();           // all waves done reading As1/Bs1[bb]
      if (pf) stage1(bb, kt + 2);             // overwrite freed buffer
      __builtin_amdgcn_s_setprio(1);
#pragma unroll
      for (int mf = 0; mf < 4; ++mf)
#pragma unroll
        for (int nf = 0; nf < 2; ++nf)
#pragma unroll
          for (int kc = 0; kc < 2; ++kc)
            acc1[mf][nf] = __builtin_amdgcn_mfma_f32_16x16x32_bf16(a[mf][kc], bq[nf][kc], acc1[mf][nf], 0, 0, 0);
      __builtin_amdgcn_s_setprio(0);
    }

    // ---- half 2: gemm2 ----
    {
      v8s a[4][2], bq[2][2];
#pragma unroll
      for (int mf = 0; mf < 4; ++mf) {
        const int r = arow + mf * 16 + l15;
#pragma unroll
        for (int kc = 0; kc < 2; ++kc)
          a[mf][kc] = *(const v8s*)&As2[bb][r * 64 + (((kc * 4 + quad) ^ (l15 & 7)) * 8)];
      }
#pragma unroll
      for (int nf = 0; nf < 2; ++nf) {
        const int r = brow + nf * 16 + l15;
#pragma unroll
        for (int kc = 0; kc < 2; ++kc)
          bq[nf][kc] = *(const v8s*)&Bs2[bb][r * 64 + (((kc * 4 + quad) ^ (l15 & 7)) * 8)];
      }
      asm volatile("s_waitcnt lgkmcnt(0)" ::: "memory");
      __builtin_amdgcn_s_barrier();           // all waves done reading As2/Bs2[bb]
      if (pf) stage2(bb, kt + 2);
      __builtin_amdgcn_s_setprio(1);
#pragma unroll
      for (int mf = 0; mf < 4; ++mf)
#pragma unroll
        for (int nf = 0; nf < 2; ++nf)
#pragma unroll
          for (int kc = 0; kc < 2; ++kc)
            acc2[mf][nf] = __builtin_amdgcn_mfma_f32_16x16x32_bf16(a[mf][kc], bq[nf][kc], acc2[mf][nf], 0, 0, 0);
      __builtin_amdgcn_s_setprio(0);
    }
  }

  float cb1[2], cb2[2];
#pragma unroll
  for (int nf = 0; nf < 2; ++nf) {
    cb1[nf] = b1v[n0 + brow + nf * 16 + l15];
    cb2[nf] = b2v[n0 + brow + nf * 16 + l15];
  }

#pragma unroll
  for (int mf = 0; mf < 4; ++mf) {
    const int rbase = m0 + arow + mf * 16 + quad * 4;
#pragma unroll
    for (int c = 0; c < 4; ++c) {
      const int row = rbase + c;
      if (row < Mrows) {
#pragma unroll
        for (int nf = 0; nf < 2; ++nf) {
          const size_t idx = (size_t)row * Ncols + n0 + brow + nf * 16 + l15;
          const float zy = acc1[mf][nf][c] + cb1[nf];
          const float zg = acc2[mf][nf][c] + cb2[nf];
          const float sg = 1.0f / (1.0f + __expf(-zg));
          Cout[idx] = X[idx] + sg * zy;
        }
      }
    }
  }
}

// ---------------- fused Q/K rope + Q/K/V bf16 repack (bf16 qkv input) -------
// Q is pre-scaled by 1/sqrt(Dh) * log2(e) so attention can use raw v_exp_f32.
__global__ __launch_bounds__(256) void k_repack_qkv(const unsigned short* __restrict__ qkv,
                                                    const float* __restrict__ fc,
                                                    unsigned short* __restrict__ qt,
                                                    unsigned short* __restrict__ kt,
                                                    unsigned short* __restrict__ vt)
{
  const int bh = blockIdx.x;
  const int b  = bh >> 4;
  const int h  = bh & 15;
  const int j0 = blockIdx.y * 64;
  const int t  = threadIdx.x;
  __shared__ float T[64][65];

  // ---- Q and K: rope -> [bh][j][d] ----
  {
    const int row  = t >> 2;
    const int dseg = (t & 3) * 16;
    const int n    = j0 + row;
    unsigned short qb[16], kb[16];
    if (n < N_) {
      const unsigned short* qp = qkv + (size_t)(b * N_ + n) * K3_ + h * 64 + dseg;
      const unsigned short* kp = qp + 1024;
      const float2* fp = (const float2*)fc + (size_t)n * 32 + dseg / 2;
      unsigned short qin[16], kin[16];
      *(uint4*)&qin[0] = *(const uint4*)qp;
      *(uint4*)&qin[8] = *(const uint4*)(qp + 8);
      *(uint4*)&kin[0] = *(const uint4*)kp;
      *(uint4*)&kin[8] = *(const uint4*)(kp + 8);
      const float qs = 0.125f * LOG2E;
#pragma unroll
      for (int j = 0; j < 8; ++j) {
        const float2 f  = fp[j];
        const float qx = bf2f(qin[2 * j]), qy = bf2f(qin[2 * j + 1]);
        qb[2 * j]     = f2bf((qx * f.x - qy * f.y) * qs);
        qb[2 * j + 1] = f2bf((qx * f.y + qy * f.x) * qs);
        const float kx = bf2f(kin[2 * j]), ky = bf2f(kin[2 * j + 1]);
        kb[2 * j]     = f2bf(kx * f.x - ky * f.y);
        kb[2 * j + 1] = f2bf(kx * f.y + ky * f.x);
      }
    } else {
#pragma unroll
      for (int j = 0; j < 16; ++j) { qb[j] = 0; kb[j] = 0; }
    }
    unsigned short* qd = qt + ((size_t)bh * NP_ + j0 + row) * 64 + dseg;
    *(uint4*)qd       = *(uint4*)&qb[0];
    *(uint4*)(qd + 8) = *(uint4*)&qb[8];
    unsigned short* kd = kt + ((size_t)bh * NP_ + j0 + row) * 64 + dseg;
    *(uint4*)kd       = *(uint4*)&kb[0];
    *(uint4*)(kd + 8) = *(uint4*)&kb[8];
  }

  // ---- V: transpose -> vt[bh][d][j] ----
#pragma unroll
  for (int l = 0; l < 4; ++l) {
    const int j  = (t >> 4) + 16 * l;
    const int jg = j0 + j;
    const int d4 = (t & 15) * 4;
    float4 v = make_float4(0.f, 0.f, 0.f, 0.f);
    if (jg < N_) {
      const ushort4 vr = *(const ushort4*)(qkv + (size_t)(b * N_ + jg) * K3_ + 2048 + h * 64 + d4);
      v = make_float4(bf2f(vr.x), bf2f(vr.y), bf2f(vr.z), bf2f(vr.w));
    }
    *(float4*)&T[j][d4] = v;
  }
  __syncthreads();
#pragma unroll
  for (int l = 0; l < 4; ++l) {
    const int d  = (t >> 4) + 16 * l;
    const int j4 = (t & 15) * 4;
    ushort4 o;
    o.x = f2bf(T[j4 + 0][d]); o.y = f2bf(T[j4 + 1][d]);
    o.z = f2bf(T[j4 + 2][d]); o.w = f2bf(T[j4 + 3][d]);
    *(ushort4*)(vt + ((size_t)bh * 64 + d) * NP_ + j0 + j4) = o;
  }
}

// ---------------- MFMA flash attention (rows 0..1023) ----------------
// S computed TRANSPOSED (A=K, B=Q); softmax in log2 domain; denominator via
// ones-MFMA. 3-buffer LDS pipeline, prefetch depth 2, counted vmcnt(4).
__global__ __launch_bounds__(256) void k_attn_mfma(const unsigned short* __restrict__ qt,
                                                   const unsigned short* __restrict__ kt,
                                                   const unsigned short* __restrict__ vt,
                                                   const float* __restrict__ Bbias,
                                                   unsigned short* __restrict__ Y)
{
  const int bh = blockIdx.x;
  const int b  = bh >> 4;
  const int i0 = blockIdx.y * 128;     // 0..896: all rows < 1024 valid
  const int t  = threadIdx.x;
  const int wr = t >> 6;
  const int lane = t & 63;
  const int l15  = lane & 15;
  const int quad = lane >> 4;

  __shared__ __align__(16) unsigned short Ks[3][64 * 64];   // XOR-swizzled [j][d]
  __shared__ __align__(16) unsigned short Vs[3][64 * 64];   // XOR-swizzled [d][j]

  const unsigned short* ktb = kt + (size_t)bh * NP_ * 64;
  const unsigned short* vtb = vt + (size_t)bh * 64 * NP_;
  const int rw0  = i0 + wr * 32;
  const int rowl = lane >> 3;          // 0..7
  const int lc   = (lane & 7) ^ rowl;  // XOR swizzle (16B chunk granularity)

  auto stage = [&](int ic, int pp) {
    const int js = ic * 64;
    gload16(ktb + (size_t)(js + wr * 16 + rowl) * 64 + lc * 8,      &Ks[pp][(wr * 16) * 64]);
    gload16(ktb + (size_t)(js + wr * 16 + 8 + rowl) * 64 + lc * 8,  &Ks[pp][(wr * 16 + 8) * 64]);
    gload16(vtb + (size_t)(wr * 16 + rowl) * NP_ + js + lc * 8,     &Vs[pp][(wr * 16) * 64]);
    gload16(vtb + (size_t)(wr * 16 + 8 + rowl) * NP_ + js + lc * 8, &Vs[pp][(wr * 16 + 8) * 64]);
  };

  // prologue: prefetch chunks 0 and 1 (issued before any other vmem op)
  stage(0, 0);
  stage(1, 1);

  // ---- Q fragments (B-operand; pre-scaled by 1/8 * log2e) ----
  v8s qf[2][2];
#pragma unroll
  for (int rt = 0; rt < 2; ++rt)
#pragma unroll
    for (int ks = 0; ks < 2; ++ks) {
      const int row = i0 + wr * 32 + rt * 16 + l15;
      qf[rt][ks] = *(const v8s*)(qt + ((size_t)bh * NP_ + row) * 64 + ks * 32 + quad * 8);
    }

  // ---- per-lane tridiagonal bias, pre-scaled to log2 domain ----
  int   rowi[2];
  float bm[2], bp[2];
#pragma unroll
  for (int rt = 0; rt < 2; ++rt) {
    const int r = i0 + wr * 32 + rt * 16 + l15;
    rowi[rt] = r;
    bm[rt] = (r > 0) ? Bbias[(size_t)r * N_ + r - 1] * LOG2E : 0.f;
    bp[rt] = Bbias[(size_t)r * N_ + r + 1] * LOG2E;   // r <= 1023 < N_-1 always
  }

  v4f o[2][4];
  v4f ol[2];   // softmax denominator accumulators (row-sums via ones-MFMA)
#pragma unroll
  for (int rt = 0; rt < 2; ++rt) {
    ol[rt] = (v4f){0.f, 0.f, 0.f, 0.f};
#pragma unroll
    for (int nt = 0; nt < 4; ++nt) o[rt][nt] = (v4f){0.f, 0.f, 0.f, 0.f};
  }
  const v4s ones = { (short)0x3F80, (short)0x3F80, (short)0x3F80, (short)0x3F80 };

  for (int ic = 0; ic < 17; ++ic) {
    const int j0 = ic * 64;
    const int p  = ic % 3;
    // wait for chunk ic's 4 loads; allow chunk ic+1's 4 to stay in flight
    if (ic < 16) asm volatile("s_waitcnt vmcnt(4)" ::: "memory");
    else         asm volatile("s_waitcnt vmcnt(0)" ::: "memory");
    __syncthreads();
    if (ic + 2 <= 16) stage(ic + 2, (ic + 2) % 3);   // depth-2 prefetch

    // ---- QK^T transposed: S^T[j][i] (already in log2 domain) ----
    v4f s[2][4];
#pragma unroll
    for (int jt = 0; jt < 4; ++jt) {
      const int rr  = jt * 16 + l15;
      const v8s kf0 = *(const v8s*)&Ks[p][rr * 64 + ((0 + quad) ^ (rr & 7)) * 8];
      const v8s kf1 = *(const v8s*)&Ks[p][rr * 64 + ((4 + quad) ^ (rr & 7)) * 8];
#pragma unroll
      for (int rt = 0; rt < 2; ++rt) {
        v4f acc = (v4f){0.f, 0.f, 0.f, 0.f};
        acc = __builtin_amdgcn_mfma_f32_16x16x32_bf16(kf0, qf[rt][0], acc, 0, 0, 0);
        acc = __builtin_amdgcn_mfma_f32_16x16x32_bf16(kf1, qf[rt][1], acc, 0, 0, 0);
        s[rt][jt] = acc;
      }
    }

    // ---- sparse tridiagonal bias (wave-uniform rare branch) ----
    if (j0 <= rw0 + 32 && j0 + 64 >= rw0) {
#pragma unroll
      for (int rt = 0; rt < 2; ++rt) {
        const int r = rowi[rt];
#pragma unroll
        for (int jt = 0; jt < 4; ++jt)
#pragma unroll
          for (int c = 0; c < 4; ++c) {
            const int j = j0 + jt * 16 + quad * 4 + c;
            float v = s[rt][jt][c];
            v += (j == r - 1) ? bm[rt] : 0.f;
            v += (j == r + 1) ? bp[rt] : 0.f;
            s[rt][jt][c] = v;
          }
      }
    }
    // ---- key mask (final chunk: padded j rows) ----
    if (ic == 16) {
#pragma unroll
      for (int jt = 0; jt < 4; ++jt)
#pragma unroll
        for (int c = 0; c < 4; ++c) {
          const bool valid = (j0 + jt * 16 + quad * 4 + c) < N_;
#pragma unroll
          for (int rt = 0; rt < 2; ++rt)
            if (!valid) s[rt][jt][c] = -1e30f;
        }
    }

    // ---- static softmax in-register; pack to PV A-frags via v_perm ----
    v4s pa[2][4];
#pragma unroll
    for (int rt = 0; rt < 2; ++rt)
#pragma unroll
      for (int jt = 0; jt < 4; ++jt) {
        float p0 = fexp2(s[rt][jt][0]);
        float p1 = fexp2(s[rt][jt][1]);
        float p2 = fexp2(s[rt][jt][2]);
        float p3 = fexp2(s[rt][jt][3]);
        const unsigned lo = __builtin_amdgcn_perm(__float_as_uint(p1), __float_as_uint(p0), 0x07060302u);
        const unsigned hi = __builtin_amdgcn_perm(__float_as_uint(p3), __float_as_uint(p2), 0x07060302u);
        v4s pv;
        ((unsigned*)&pv)[0] = lo;
        ((unsigned*)&pv)[1] = hi;
        pa[rt][jt] = pv;
      }

    // ---- PV: K=16 MFMAs, A from registers, B (V) from LDS b64 ----
#pragma unroll
    for (int jt = 0; jt < 4; ++jt) {
      v4s vf[4];
#pragma unroll
      for (int nt = 0; nt < 4; ++nt) {
        const int d  = nt * 16 + l15;
        const int pc = (jt * 2 + (quad >> 1)) ^ (d & 7);   // physical 16B chunk
        vf[nt] = *(const v4s*)&Vs[p][d * 64 + pc * 8 + (quad & 1) * 4];
      }
#pragma unroll
      for (int rt = 0; rt < 2; ++rt) {
        ol[rt] = __builtin_amdgcn_mfma_f32_16x16x16bf16_1k(pa[rt][jt], ones, ol[rt], 0, 0, 0);
#pragma unroll
        for (int nt = 0; nt < 4; ++nt)
          o[rt][nt] = __builtin_amdgcn_mfma_f32_16x16x16bf16_1k(pa[rt][jt], vf[nt], o[rt][nt], 0, 0, 0);
      }
    }
  }

  // ---- epilogue: denominator already in correct lane slots ----
#pragma unroll
  for (int rt = 0; rt < 2; ++rt) {
#pragma unroll
    for (int c = 0; c < 4; ++c) {
      const int row = i0 + wr * 32 + rt * 16 + quad * 4 + c;
      const float rl = 1.0f / ol[rt][c];
#pragma unroll
      for (int nt = 0; nt < 4; ++nt)
        Y[(size_t)(b * N_ + row) * D_ + (bh & 15) * 64 + nt * 16 + l15] = f2bf(o[rt][nt][c] * rl);
    }
  }
}

// ---------------- attention for the single tail q-row (row 1024) ----------
__global__ __launch_bounds__(64) void k_attn_row(const unsigned short* __restrict__ qt,
                                                 const unsigned short* __restrict__ kt,
                                                 const unsigned short* __restrict__ vt,
                                                 const float* __restrict__ Bbias,
                                                 unsigned short* __restrict__ Y)
{
  const int bh   = blockIdx.x;
  const int b    = bh >> 4;
  const int h    = bh & 15;
  const int lane = threadIdx.x;
  constexpr int R = N_ - 1;   // 1024

  __shared__ float Qs[64];
  __shared__ float P[NP_];

  Qs[lane] = bf2f(qt[((size_t)bh * NP_ + R) * 64 + lane]);
  __syncthreads();

  const float bmv = Bbias[(size_t)R * N_ + R - 1] * LOG2E;
  const unsigned short* ktb = kt + (size_t)bh * NP_ * 64;

  float lsum = 0.f;
#pragma unroll
  for (int it = 0; it < 17; ++it) {
    const int j = it * 64 + lane;
    const v8s* kr = (const v8s*)(ktb + (size_t)j * 64);
    float s = 0.f;
#pragma unroll
    for (int c = 0; c < 8; ++c) {
      const v8s kv = kr[c];
#pragma unroll
      for (int e = 0; e < 8; ++e)
        s += Qs[c * 8 + e] * bf2f((unsigned short)kv[e]);
    }
    if (j == R - 1) s += bmv;
    float p = (j < N_) ? fexp2(s) : 0.f;
    P[j] = p;
    lsum += p;
  }
  const float linv = 1.0f / wave_sum64(lsum);
  __syncthreads();

  const unsigned short* vr = vt + ((size_t)bh * 64 + lane) * NP_;
  float o = 0.f;
#pragma unroll
  for (int it = 0; it < 136; ++it) {   // 1088 / 8
    const v8s vv = *(const v8s*)(vr + it * 8);
#pragma unroll
    for (int e = 0; e < 8; ++e)
      o += P[it * 8 + e] * bf2f((unsigned short)vv[e]);
  }
  Y[(size_t)(b * N_ + R) * D_ + h * 64 + lane] = f2bf(o * linv);
}

extern "C" void kernel_launch(void* const* d_in, const int* in_sizes, int n_in,
                              void* d_out, int out_size, void* d_ws, size_t ws_size,
                              hipStream_t stream)
{
  const float* x      = (const float*)d_in[0];
  const float* fc     = (const float*)d_in[1];
  const float* g      = (const float*)d_in[2];
  const float* qkv_w  = (const float*)d_in[3];
  const float* qkv_b  = (const float*)d_in[4];
  const float* out_w  = (const float*)d_in[5];
  const float* out_b  = (const float*)d_in[6];
  const float* gate_w = (const float*)d_in[7];
  const float* gate_b = (const float*)d_in[8];
  const float* Bbias  = (const float*)d_in[9];
  float* out = (float*)d_out;

  // workspace (~120 MB, all bf16)
  unsigned short* qkvb    = (unsigned short*)d_ws;             // M_*3072
  unsigned short* ybf     = qkvb + (size_t)M_ * K3_;           // M_*1024
  unsigned short* qt      = ybf + (size_t)M_ * D_;             // 128*NP_*64
  unsigned short* kt      = qt + (size_t)128 * NP_ * 64;
  unsigned short* vt      = kt + (size_t)128 * NP_ * 64;
  unsigned short* qkvw_bf = vt + (size_t)128 * NP_ * 64;       // 3072*1024
  unsigned short* wo_bf   = qkvw_bf + (size_t)K3_ * D_;        // 1024*1024
  unsigned short* wg_bf   = wo_bf + (size_t)D_ * D_;           // 1024*1024
  unsigned short* hbf     = wg_bf + (size_t)D_ * D_;           // M_*1024

  // 0. weight conversion to bf16 (single launch)
  k_f2bf_all<<<(K3_ * D_ + 2 * D_ * D_) / 1024, 256, 0, stream>>>(
      qkv_w, out_w, gate_w, qkvw_bf, wo_bf, wg_bf);

  // 1. zero-centered RMSNorm -> bf16
  k_rmsnorm<<<M_, 256, 0, stream>>>(x, g, hbf);

  // 2. qkv projection (256x256 pipelined bf16 MFMA) -> bf16 qkv
  dim3 g1(K3_ / 256, (M_ + 255) / 256);        // (12, 33)
  k_gemm_qkv<<<g1, 512, 0, stream>>>(hbf, qkvw_bf, qkv_b, qkvb, M_, K3_, D_);

  // 3. Q/K rope + Q/K/V bf16 repack
  dim3 gv_(B_ * H_, NP_ / 64);                 // (128, 17)
  k_repack_qkv<<<gv_, 256, 0, stream>>>(qkvb, fc, qt, kt, vt);

  // 4. attention: rows 0..1023 (MFMA) + row 1024 (1-wave tail kernel)
  dim3 g2(B_ * H_, 8);                         // (128, 8)
  k_attn_mfma<<<g2, 256, 0, stream>>>(qt, kt, vt, Bbias, ybf);
  k_attn_row<<<B_ * H_, 64, 0, stream>>>(qt, kt, vt, Bbias, ybf);

  // 5+6. fused out-proj + gate-proj + sigmoid-gate + residual
  dim3 g3(D_ / 128, (M_ + 127) / 128);         // (8, 65)
  k_gemm_outgate<<<g3, 512, 0, stream>>>(ybf, hbf, wo_bf, wg_bf, out_b, gate_b,
                                         x, out, M_);
}